// Round 6
// baseline (744.066 us; speedup 1.0000x reference)
//
#include <hip/hip_runtime.h>

#define NB 2
#define CCH 64
#define LL 8
#define HH 160
#define WW 160
#define PP 8
#define NPH 20
#define NPW 20
#define NPAT (NB*NPH*NPW)      // 800
#define NE 8
#define HWX (HH*WW)            // 25600
#define CSTRIDE (LL*HWX)       // 204800

typedef float f32x4  __attribute__((ext_vector_type(4)));
typedef float f32x16 __attribute__((ext_vector_type(16)));
typedef short bf16x8 __attribute__((ext_vector_type(8)));

__device__ __host__ __forceinline__ unsigned short f2bf(float f) {
    unsigned u = __builtin_bit_cast(unsigned, f);
    u = (u + 0x7FFFu + ((u >> 16) & 1u)) >> 16;
    return (unsigned short)u;
}
template<int CTRL>
__device__ __forceinline__ float dpp0(float v) {   // old=0, bound_ctrl=true
    return __builtin_bit_cast(float, __builtin_amdgcn_update_dpp(
        0, __builtin_bit_cast(int, v), CTRL, 0xF, 0xF, true));
}
__device__ __forceinline__ float dpp_xor1(float v) {  // quad_perm [1,0,3,2]
    int s = __builtin_bit_cast(int, v);
    return __builtin_bit_cast(float, __builtin_amdgcn_update_dpp(s, s, 0xB1, 0xF, 0xF, false));
}
__device__ __forceinline__ float wsum64(float v) {
    v += dpp0<0x111>(v); v += dpp0<0x112>(v); v += dpp0<0x114>(v);
    v += dpp0<0x118>(v); v += dpp0<0x142>(v); v += dpp0<0x143>(v);
    return __builtin_bit_cast(float, __builtin_amdgcn_readlane(__builtin_bit_cast(int, v), 63));
}
__device__ __forceinline__ float bperm(int a4, float v) {
    return __builtin_bit_cast(float, __builtin_amdgcn_ds_bpermute(a4, __builtin_bit_cast(int, v)));
}

// ---------------- Prep ----------------
__global__ __launch_bounds__(256)
void prep_kernel(const float* __restrict__ pwin_w, const float* __restrict__ pwout_w,
                 const float* __restrict__ dw_w,
                 unsigned short* __restrict__ w1t, unsigned short* __restrict__ w2t,
                 float* __restrict__ w1sum, unsigned short* __restrict__ mx, int full)
{
    int idx = blockIdx.x * 256 + threadIdx.x;
    if (full) {
        int j = idx & 7, lane = (idx >> 3) & 63, ks = (idx >> 9) & 1;
        int mt = (idx >> 10) & 3, c = (idx >> 12) & 63, e = idx >> 18;
        int m = 16*mt + (lane & 15);
        int k = ks*32 + ((lane >> 4) << 3) + j;
        int di = (k >> 3) - (m >> 3) + 3;
        int dj = (k & 7) - (m & 7) + 3;
        float v = 0.f;
        if (di >= 0 && di < 7 && dj >= 0 && dj < 7)
            v = dw_w[(e*CCH + c)*49 + di*7 + dj];
        mx[idx] = f2bf(v);
        if (idx < NE*128) {
            int e2 = idx >> 7, dp = idx & 127;
            int orig = (dp & 1) ? 64 + (dp >> 1) : (dp >> 1);
            float s = 0.f;
            for (int cc = 0; cc < 64; ++cc) s += pwin_w[(e2 << 13) + orig*64 + cc];
            w1sum[idx] = s;
        }
    }
    if (idx < NE*128*64) {
        int e = idx >> 13, r = (idx >> 6) & 127, c = idx & 63;
        int orig = (r & 1) ? 64 + (r >> 1) : (r >> 1);
        w1t[idx] = f2bf(pwin_w[(e << 13) + orig*64 + c]);
    }
    if (idx < NE*64*64) w2t[idx] = f2bf(pwout_w[idx]);
}

// ---------------- Router ----------------
__global__ __launch_bounds__(256)
void router_kernel(const float* __restrict__ x,
                   const float* __restrict__ rw,
                   const float* __restrict__ rb,
                   int* __restrict__ sel_idx,
                   float* __restrict__ sel_w)
{
    int n = blockIdx.x;
    int b = n / (NPH*NPW);
    int rem = n - b*(NPH*NPW);
    int ph = rem / NPW, pw = rem - ph*NPW;
    int t = threadIdx.x;
    int c = t >> 2, part = t & 3;

    const float* xl0 = x + ((size_t)(b*CCH + c)*LL)*HWX + (size_t)(ph*PP)*WW + pw*PP;
    float s = 0.f;
    for (int l = part*2; l < part*2 + 2; ++l) {
        const float* xl = xl0 + (size_t)l*HWX;
        #pragma unroll
        for (int i = 0; i < 8; ++i) {
            float4 v0 = *(const float4*)(xl + i*WW);
            float4 v1 = *(const float4*)(xl + i*WW + 4);
            s += v0.x+v0.y+v0.z+v0.w + v1.x+v1.y+v1.z+v1.w;
        }
    }
    s += __shfl_xor(s, 1);
    s += __shfl_xor(s, 2);

    __shared__ float meanc[CCH];
    __shared__ float logits[NE];
    if (part == 0) meanc[c] = s * (1.f/512.f);
    __syncthreads();
    if (t < NE) {
        float acc = rb[t];
        for (int cc = 0; cc < CCH; ++cc) acc += meanc[cc] * rw[t*CCH + cc];
        logits[t] = acc;
    }
    __syncthreads();
    if (t == 0) {
        float m0 = -1e30f; int i0 = 0;
        #pragma unroll
        for (int e = 0; e < NE; ++e) { float v = logits[e]; if (v > m0) { m0 = v; i0 = e; } }
        float m1 = -1e30f; int i1 = 0;
        #pragma unroll
        for (int e = 0; e < NE; ++e) { if (e != i0) { float v = logits[e]; if (v > m1) { m1 = v; i1 = e; } } }
        float dd = __expf(m1 - m0);
        float inv = 1.f / (1.f + dd);
        sel_idx[n*2]   = i0;  sel_idx[n*2+1] = i1;
        sel_w[n*2]     = inv; sel_w[n*2+1]   = dd * inv;
    }
}

// ---------------- MFMA path: one block per patch; x staged in LDS once ----------------
// LDS 144 KiB: xb bf16 [64c][8r][8l][8j] (64K) | Ydw bf16 [8l][64s][64c] swz (64K) | G/obuf (16K)
__global__ __launch_bounds__(256)
void moe_mfma(const float* __restrict__ x,
              const float* __restrict__ ln_g,
              const float* __restrict__ ln_b,
              const float* __restrict__ pwin_b,
              const float* __restrict__ pwout_b,
              const unsigned short* __restrict__ w1t,
              const unsigned short* __restrict__ w2t,
              const float* __restrict__ w1sum,
              const unsigned short* __restrict__ mx,
              const int* __restrict__ sel_idx,
              const float* __restrict__ sel_w,
              float* __restrict__ out)
{
    __shared__ __align__(16) unsigned smem[36864];     // 144 KiB
    unsigned* xb  = smem;                              // [0, 16384) dwords
    unsigned* Ydw = smem + 16384;                      // [16384, 32768) dwords
    unsigned* G   = smem + 32768;                      // 2048 dwords used
    float* obuf   = (float*)(smem + 32768);            // 4096 dwords (aliases G)

    int n = blockIdx.x;
    int b = n / (NPH*NPW);
    int rem = n - b*(NPH*NPW);
    int ph = rem / NPW, pw = rem - ph*NPW;

    int t = threadIdx.x;
    int lane = t & 63;
    int q = __builtin_amdgcn_readfirstlane(t >> 6);
    int cbase = q*16;
    int laneM = lane & 31, hi = lane >> 5;
    int col16 = lane & 15, grp = lane >> 4;
    int i0 = lane >> 3, j0 = lane & 7;

    // zero-fill LDS (uninit-read insurance)
    {
        uint4 zz; zz.x = 0; zz.y = 0; zz.z = 0; zz.w = 0;
        uint4* zp = (uint4*)smem;
        #pragma unroll
        for (int i = 0; i < 36; ++i) zp[t + 256*i] = zz;
    }
    __syncthreads();

    size_t xpb = ((size_t)(b*CCH)*LL)*HWX + (size_t)(ph*PP)*WW + pw*PP;

    // ---- stage x -> xb (bf16, conv-fragment-friendly layout), once per block ----
    // chunk it: c = it>>6, l = (it>>3)&7, r = it&7 ; dword = c*256 + r*32 + l*4
    #pragma unroll 4
    for (int k2 = 0; k2 < 16; ++k2) {
        int it = t + 256*k2;
        int c = it >> 6, l = (it >> 3) & 7, r = it & 7;
        const float* rp = x + xpb + (size_t)c*CSTRIDE + (size_t)l*HWX + r*WW;
        float4 v0 = *(const float4*)(rp);
        float4 v1 = *(const float4*)(rp + 4);
        uint4 bu;
        bu.x = (unsigned)f2bf(v0.x) | ((unsigned)f2bf(v0.y) << 16);
        bu.y = (unsigned)f2bf(v0.z) | ((unsigned)f2bf(v0.w) << 16);
        bu.z = (unsigned)f2bf(v1.x) | ((unsigned)f2bf(v1.y) << 16);
        bu.w = (unsigned)f2bf(v1.z) | ((unsigned)f2bf(v1.w) << 16);
        *(uint4*)&xb[c*256 + r*32 + l*4] = bu;
    }

    int e0 = __builtin_amdgcn_readfirstlane(sel_idx[n*2]);
    int e1 = __builtin_amdgcn_readfirstlane(sel_idx[n*2+1]);
    float w0 = sel_w[n*2], w1 = sel_w[n*2+1];

    int leff = lane & 7;
    bool wmask = col16 < 8;

    int dprime = 32*q + laneM;
    int borig  = (dprime & 1) ? 64 + (dprime >> 1) : (dprime >> 1);
    int cn     = 32*(q >> 1) + laneM;
    bool oddl  = (lane & 1) != 0;
    int kg     = 16*q + (laneM >> 1);
    int kdg    = kg >> 1, kbit = kg & 1;
    int srow_b = (oddl ? 32 : 0) + 4*hi;

    #pragma unroll 1
    for (int pass = 0; pass < 2; ++pass) {
        int e    = pass ? e1 : e0;
        float we = pass ? w1 : w0;

        __syncthreads();   // pass0: xb staged; pass1: prev pass's Ydw reads done

        // ---- depthwise conv via MFMA (batched over l) + LN -> Ydw ----
        const unsigned short* mxe = mx + (((size_t)(e*CCH + cbase)) << 12);
        #pragma unroll 2
        for (int m = 0; m < 16; ++m) {
            int c = cbase + m;
            const unsigned short* mxc = mxe + ((size_t)m << 12);
            f32x4 acc[4];
            #pragma unroll
            for (int mt = 0; mt < 4; ++mt) { acc[mt][0]=0.f; acc[mt][1]=0.f; acc[mt][2]=0.f; acc[mt][3]=0.f; }
            #pragma unroll
            for (int ks = 0; ks < 2; ++ks) {
                uint4 bu = *(const uint4*)&xb[c*256 + (4*ks + grp)*32 + leff*4];
                bf16x8 bf = __builtin_bit_cast(bf16x8, bu);
                #pragma unroll
                for (int mt = 0; mt < 4; ++mt) {
                    uint4 au = *(const uint4*)(mxc + ((mt*2 + ks) << 9) + lane*8);
                    acc[mt] = __builtin_amdgcn_mfma_f32_16x16x32_bf16(
                        __builtin_bit_cast(bf16x8, au), bf, acc[mt], 0, 0, 0);
                }
            }
            // LN stats over the 64 spatial outputs of this (c, l)
            float sum = 0.f, sq = 0.f;
            #pragma unroll
            for (int mt = 0; mt < 4; ++mt)
                #pragma unroll
                for (int r = 0; r < 4; ++r) { float v = acc[mt][r]; sum += v; sq = fmaf(v, v, sq); }
            sum += __shfl_xor(sum, 16); sum += __shfl_xor(sum, 32);
            sq  += __shfl_xor(sq, 16);  sq  += __shfl_xor(sq, 32);
            float mu  = sum * 0.015625f;
            float var = fmaxf(fmaf(sq, 0.015625f, -mu*mu), 0.f);
            float inv = rsqrtf(var + 1e-5f);
            float nmu = -mu * inv;
            if (wmask) {
                unsigned short* Yh = (unsigned short*)Ydw;
                #pragma unroll
                for (int mt = 0; mt < 4; ++mt)
                    #pragma unroll
                    for (int r = 0; r < 4; ++r) {
                        int s = 16*mt + 4*grp + r;
                        float yv = fmaf(acc[mt][r], inv, nmu);
                        int dwi = (c >> 1) ^ ((((s & 7) ^ leff)) << 2);
                        int half = (leff*8192 + s*128 + 4*dwi + 2*(c & 1)) >> 1;
                        Yh[half] = f2bf(yv);
                    }
            }
        }

        // ---- per-pass GEMM constants ----
        const unsigned short* w1e = w1t + ((size_t)e << 13);
        const unsigned short* w2e = w2t + ((size_t)e << 12);
        uint4 b1f[4], b2f[4];
        #pragma unroll
        for (int ks = 0; ks < 4; ++ks)
            b1f[ks] = *(const uint4*)(w1e + dprime*64 + 16*ks + 8*hi);
        #pragma unroll
        for (int ks = 0; ks < 4; ++ks)
            b2f[ks] = *(const uint4*)(w2e + cn*64 + 16*ks + 8*hi);
        float bias1 = pwin_b[e*128 + borig];
        float bias2 = pwout_b[e*64 + cn];
        float w1s   = w1sum[e*128 + dprime];
        float g0v[16], a0c[16], g1v[16], a1c[16];
        #pragma unroll
        for (int r = 0; r < 16; ++r) {
            int sr = (r & 3) + 8*(r >> 2) + 4*hi;
            g0v[r] = ln_g[e*64 + sr];
            a0c[r] = fmaf(ln_b[e*64 + sr], w1s, bias1);
            g1v[r] = ln_g[e*64 + 32 + sr];
            a1c[r] = fmaf(ln_b[e*64 + 32 + sr], w1s, bias1);
        }

        __syncthreads();   // Ydw complete

        #pragma unroll 1
        for (int l = 0; l < 8; ++l) {
            int lbase = l*2048;
            int lsw = l << 2;
            // ---- GEMM1 ----
            f32x16 acc0, acc1;
            #pragma unroll
            for (int i = 0; i < 16; ++i) { acc0[i] = 0.f; acc1[i] = 0.f; }
            #pragma unroll
            for (int ks = 0; ks < 4; ++ks) {
                int kd = 8*ks + 4*hi;
                int sA = laneM, sB = 32 + laneM;
                uint4 a0u = *(const uint4*)&Ydw[lbase + sA*32 + ((kd ^ ((sA & 7) << 2)) ^ lsw)];
                uint4 a1u = *(const uint4*)&Ydw[lbase + sB*32 + ((kd ^ ((sB & 7) << 2)) ^ lsw)];
                bf16x8 bv = __builtin_bit_cast(bf16x8, b1f[ks]);
                acc0 = __builtin_amdgcn_mfma_f32_32x32x16_bf16(__builtin_bit_cast(bf16x8, a0u), bv, acc0, 0, 0, 0);
                acc1 = __builtin_amdgcn_mfma_f32_32x32x16_bf16(__builtin_bit_cast(bf16x8, a1u), bv, acc1, 0, 0, 0);
            }
            __syncthreads();   // prev-l obuf reads done
            // ---- gate (folded LN affine) ----
            #pragma unroll
            for (int r = 0; r < 16; ++r) {
                float h0 = fmaf(acc0[r], g0v[r], a0c[r]);
                float h1 = fmaf(acc1[r], g1v[r], a1c[r]);
                float p0 = dpp_xor1(h0);
                float p1 = dpp_xor1(h1);
                float A0 = oddl ? p0 : h0, G0 = oddl ? h0 : p0;
                float A1 = oddl ? p1 : h1, G1 = oddl ? h1 : p1;
                float ga = __fdividef(A0, 1.f + __expf(-A0)) * G0;
                float gb = __fdividef(A1, 1.f + __expf(-A1)) * G1;
                float val = oddl ? gb : ga;
                int srow = srow_b + (r & 3) + 8*(r >> 2);
                int gd = srow*32 + (kdg ^ ((srow & 7) << 2));
                ((unsigned short*)G)[gd*2 + kbit] = f2bf(val);
            }
            __syncthreads();   // G ready
            // ---- GEMM2 ----
            f32x16 gacc;
            #pragma unroll
            for (int i = 0; i < 16; ++i) gacc[i] = 0.f;
            #pragma unroll
            for (int ks = 0; ks < 4; ++ks) {
                int sG = 32*(q & 1) + laneM;
                int kd = 8*ks + 4*hi;
                uint4 ag = *(const uint4*)&G[sG*32 + (kd ^ ((sG & 7) << 2))];
                gacc = __builtin_amdgcn_mfma_f32_32x32x16_bf16(
                    __builtin_bit_cast(bf16x8, ag), __builtin_bit_cast(bf16x8, b2f[ks]), gacc, 0, 0, 0);
            }
            __syncthreads();   // all G reads done (obuf aliases G)
            // ---- obuf transpose write ----
            {
                int s_base = 32*(q & 1) + 4*hi;
                #pragma unroll
                for (int r = 0; r < 16; ++r) {
                    int s = s_base + (r & 3) + 8*(r >> 2);
                    obuf[cn*64 + (s ^ (cn & 31))] = we * (gacc[r] + bias2);
                }
            }
            __syncthreads();   // obuf ready
            // ---- global store ----
            size_t gl = xpb + (size_t)l*HWX + (size_t)i0*WW + j0;
            #pragma unroll
            for (int m2 = 0; m2 < 16; ++m2) {
                int c = cbase + m2;
                float v = obuf[c*64 + (lane ^ (c & 31))];
                size_t ga = gl + (size_t)c*CSTRIDE;
                if (pass == 0) out[ga] = v + x[ga];
                else           out[ga] += v;
            }
        }
    }
}

// ---------------- Fallback: verified round-3 kernel (one block per (patch,l)) ----------------
__global__ __launch_bounds__(256, 4)
void moe_r3(const float* __restrict__ x,
            const float* __restrict__ dw_w,
            const float* __restrict__ dw_b,
            const float* __restrict__ ln_g,
            const float* __restrict__ ln_b,
            const float* __restrict__ pwin_b,
            const float* __restrict__ pwout_b,
            const unsigned short* __restrict__ w1t,
            const unsigned short* __restrict__ w2t,
            const int* __restrict__ sel_idx,
            const float* __restrict__ sel_w,
            float* __restrict__ out)
{
    __shared__ __align__(16) unsigned smem[8192];
    float* xin   = (float*)smem;
    unsigned* Y  = smem + 4096;
    unsigned* G  = smem + 6144;
    float* obuf  = (float*)(smem + 4096);

    int bid = blockIdx.x;
    int n = bid >> 3;
    int l = bid & 7;
    int b = n / (NPH*NPW);
    int rem = n - b*(NPH*NPW);
    int ph = rem / NPW, pw = rem - ph*NPW;

    int t = threadIdx.x;
    int lane = t & 63;
    int q = __builtin_amdgcn_readfirstlane(t >> 6);
    int cbase = q*16;
    int i0 = lane >> 3, j0 = lane & 7;
    int laneM = lane & 31, hi = lane >> 5;

    bool l1ok = j0 < 7, l2ok = j0 < 6, l3ok = j0 < 5;
    bool r1ok = j0 > 0, r2ok = j0 > 1, r3ok = j0 > 2;
    bool u1ok = i0 < 7, u2ok = i0 < 6, u3ok = i0 < 5;
    bool d1ok = i0 > 0, d2ok = i0 > 1, d3ok = i0 > 2;
    int aup1 = ((lane + 8)  & 63) << 2, aup2 = ((lane + 16) & 63) << 2, aup3 = ((lane + 24) & 63) << 2;
    int adn1 = ((lane - 8)  & 63) << 2, adn2 = ((lane - 16) & 63) << 2, adn3 = ((lane - 24) & 63) << 2;

    size_t pbase = ((size_t)(b*CCH)*LL + l)*HWX + (size_t)(ph*PP)*WW + pw*PP;
    for (int idx4 = t; idx4 < 1024; idx4 += 256) {
        int c = idx4 >> 4, r = idx4 & 15, ii = r >> 1, jj = (r & 1)*4;
        float4 v = *(const float4*)(x + pbase + (size_t)c*CSTRIDE + ii*WW + jj);
        *(float4*)(xin + c*64 + ii*8 + jj) = v;
    }

    int e0 = __builtin_amdgcn_readfirstlane(sel_idx[n*2]);
    int e1 = __builtin_amdgcn_readfirstlane(sel_idx[n*2+1]);
    float w0 = sel_w[n*2], w1 = sel_w[n*2+1];

    f32x16 out_acc;
    #pragma unroll
    for (int i = 0; i < 16; ++i) out_acc[i] = 0.f;

    int dprime = 32*q + laneM;
    int borig  = (dprime & 1) ? 64 + (dprime >> 1) : (dprime >> 1);
    int cn     = 32*(q >> 1) + laneM;
    int xv     = (lane & 7) << 2;
    bool oddl  = (lane & 1) != 0;
    int kg     = 16*q + (laneM >> 1);
    int kdg    = kg >> 1, kbit = kg & 1;
    int srow_b = (oddl ? 32 : 0) + 4*hi;

    #pragma unroll 1
    for (int pass = 0; pass < 2; ++pass) {
        int e = pass ? e1 : e0;
        float we = pass ? w1 : w0;

        const unsigned short* w1e = w1t + ((size_t)e << 13);
        const unsigned short* w2e = w2t + ((size_t)e << 12);
        uint4 b1f[4], b2f[4];
        #pragma unroll
        for (int ks = 0; ks < 4; ++ks)
            b1f[ks] = *(const uint4*)(w1e + (32*q + laneM)*64 + 16*ks + 8*hi);
        #pragma unroll
        for (int ks = 0; ks < 4; ++ks)
            b2f[ks] = *(const uint4*)(w2e + cn*64 + 16*ks + 8*hi);
        float bias1 = pwin_b[e*128 + borig];
        float bias2 = pwout_b[e*64 + cn];
        float lng = ln_g[e*64 + lane];
        float lnb = ln_b[e*64 + lane];

        __syncthreads();

        unsigned ypack[8];
        #pragma unroll
        for (int i = 0; i < 8; ++i) ypack[i] = 0u;

        #pragma unroll
        for (int m = 0; m < 16; ++m) {
            int c = cbase + m;
            const float* wr = dw_w + ((size_t)e*CCH + c)*49;
            float v = xin[c*64 + lane];
            float xl1 = dpp0<0x101>(v); xl1 = l1ok ? xl1 : 0.f;
            float xl2 = dpp0<0x102>(v); xl2 = l2ok ? xl2 : 0.f;
            float xl3 = dpp0<0x103>(v); xl3 = l3ok ? xl3 : 0.f;
            float xr1 = dpp0<0x111>(v); xr1 = r1ok ? xr1 : 0.f;
            float xr2 = dpp0<0x112>(v); xr2 = r2ok ? xr2 : 0.f;
            float xr3 = dpp0<0x113>(v); xr3 = r3ok ? xr3 : 0.f;
            float S0,S1,S2,S3,S4,S5,S6;
            #define ROW1D(SS, di) { const float* w7 = wr + (di)*7;            \
                float a = xr3 * w7[0];  a = fmaf(xr2, w7[1], a);              \
                a = fmaf(xr1, w7[2], a); a = fmaf(v,  w7[3], a);              \
                a = fmaf(xl1, w7[4], a); a = fmaf(xl2, w7[5], a);             \
                a = fmaf(xl3, w7[6], a); SS = a; }
            ROW1D(S0,0) ROW1D(S1,1) ROW1D(S2,2) ROW1D(S3,3) ROW1D(S4,4) ROW1D(S5,5) ROW1D(S6,6)
            #undef ROW1D
            float o = S3 + dw_b[(size_t)e*CCH + c];
            float p;
            p = bperm(aup1, S4); o += u1ok ? p : 0.f;
            p = bperm(aup2, S5); o += u2ok ? p : 0.f;
            p = bperm(aup3, S6); o += u3ok ? p : 0.f;
            p = bperm(adn1, S2); o += d1ok ? p : 0.f;
            p = bperm(adn2, S1); o += d2ok ? p : 0.f;
            p = bperm(adn3, S0); o += d3ok ? p : 0.f;
            float ssum = wsum64(o);
            float ssq  = wsum64(o*o);
            float mu  = ssum * 0.015625f;
            float var = ssq  * 0.015625f - mu*mu;
            float inv = rsqrtf(var + 1e-5f);
            float yv  = (o - mu) * inv * lng + lnb;
            ypack[m >> 1] |= ((unsigned)f2bf(yv)) << ((m & 1) * 16);
        }
        {
            uint4 v0; v0.x = ypack[0]; v0.y = ypack[1]; v0.z = ypack[2]; v0.w = ypack[3];
            uint4 v1; v1.x = ypack[4]; v1.y = ypack[5]; v1.z = ypack[6]; v1.w = ypack[7];
            *(uint4*)&Y[lane*32 + ((8*q + 0) ^ xv)] = v0;
            *(uint4*)&Y[lane*32 + ((8*q + 4) ^ xv)] = v1;
        }
        __syncthreads();

        f32x16 acc0, acc1;
        #pragma unroll
        for (int i = 0; i < 16; ++i) { acc0[i] = 0.f; acc1[i] = 0.f; }
        #pragma unroll
        for (int ks = 0; ks < 4; ++ks) {
            int kd = 8*ks + 4*hi;
            int s0 = laneM, s1 = 32 + laneM;
            uint4 a0 = *(const uint4*)&Y[s0*32 + (kd ^ ((s0 & 7) << 2))];
            uint4 a1 = *(const uint4*)&Y[s1*32 + (kd ^ ((s1 & 7) << 2))];
            bf16x8 bv = __builtin_bit_cast(bf16x8, b1f[ks]);
            acc0 = __builtin_amdgcn_mfma_f32_32x32x16_bf16(__builtin_bit_cast(bf16x8, a0), bv, acc0, 0, 0, 0);
            acc1 = __builtin_amdgcn_mfma_f32_32x32x16_bf16(__builtin_bit_cast(bf16x8, a1), bv, acc1, 0, 0, 0);
        }
        #pragma unroll
        for (int r = 0; r < 16; ++r) {
            float h0 = acc0[r] + bias1;
            float h1 = acc1[r] + bias1;
            float p0 = dpp_xor1(h0);
            float p1 = dpp_xor1(h1);
            float a0 = oddl ? p0 : h0, g0 = oddl ? h0 : p0;
            float a1 = oddl ? p1 : h1, g1 = oddl ? h1 : p1;
            float ga = __fdividef(a0, 1.f + __expf(-a0)) * g0;
            float gb = __fdividef(a1, 1.f + __expf(-a1)) * g1;
            float val = oddl ? gb : ga;
            int srow = srow_b + (r & 3) + 8*(r >> 2);
            int gd = srow*32 + (kdg ^ ((srow & 7) << 2));
            ((unsigned short*)G)[gd*2 + kbit] = f2bf(val);
        }
        __syncthreads();

        f32x16 gacc;
        #pragma unroll
        for (int i = 0; i < 16; ++i) gacc[i] = 0.f;
        #pragma unroll
        for (int ks = 0; ks < 4; ++ks) {
            int s = 32*(q & 1) + laneM;
            int kd = 8*ks + 4*hi;
            uint4 ag = *(const uint4*)&G[s*32 + (kd ^ ((s & 7) << 2))];
            gacc = __builtin_amdgcn_mfma_f32_32x32x16_bf16(
                __builtin_bit_cast(bf16x8, ag), __builtin_bit_cast(bf16x8, b2f[ks]), gacc, 0, 0, 0);
        }
        #pragma unroll
        for (int r = 0; r < 16; ++r) out_acc[r] += we * (gacc[r] + bias2);
    }

    __syncthreads();
    {
        int s_base = 32*(q & 1) + 4*hi;
        #pragma unroll
        for (int r = 0; r < 16; ++r) {
            int s = s_base + (r & 3) + 8*(r >> 2);
            obuf[cn*64 + (s ^ (cn & 31))] = out_acc[r];
        }
    }
    __syncthreads();
    #pragma unroll
    for (int m = 0; m < 16; ++m) {
        int c = cbase + m;
        float val = obuf[c*64 + (lane ^ (c & 31))] + xin[c*64 + lane];
        out[pbase + (size_t)c*CSTRIDE + i0*WW + j0] = val;
    }
}

extern "C" void kernel_launch(void* const* d_in, const int* in_sizes, int n_in,
                              void* d_out, int out_size, void* d_ws, size_t ws_size,
                              hipStream_t stream) {
    const float* x        = (const float*)d_in[0];
    const float* router_w = (const float*)d_in[1];
    const float* router_b = (const float*)d_in[2];
    const float* dw_w     = (const float*)d_in[3];
    const float* dw_b     = (const float*)d_in[4];
    const float* ln_g     = (const float*)d_in[5];
    const float* ln_b     = (const float*)d_in[6];
    const float* pwin_w   = (const float*)d_in[7];
    const float* pwin_b   = (const float*)d_in[8];
    const float* pwout_w  = (const float*)d_in[9];
    const float* pwout_b  = (const float*)d_in[10];
    float* out = (float*)d_out;

    char* ws = (char*)d_ws;
    int*            sel_idx = (int*)ws;                        // [0, 6400)
    float*          sel_w   = (float*)(ws + 6400);             // [6400, 12800)
    unsigned short* w1t     = (unsigned short*)(ws + 12800);   // 131072 B
    unsigned short* w2t     = (unsigned short*)(ws + 143872);  // 65536 B
    float*          w1sum   = (float*)(ws + 209408);           // 4096 B
    unsigned short* mx      = (unsigned short*)(ws + 213504);  // 4 MiB -> ends 4407808

    const size_t NEED_FULL = 4407808;
    int full = (ws_size >= NEED_FULL) ? 1 : 0;

    prep_kernel<<<full ? 8192 : 256, 256, 0, stream>>>(pwin_w, pwout_w, dw_w,
                                                       w1t, w2t, w1sum, mx, full);
    router_kernel<<<NPAT, 256, 0, stream>>>(x, router_w, router_b, sel_idx, sel_w);
    if (full) {
        moe_mfma<<<NPAT, 256, 0, stream>>>(x, ln_g, ln_b, pwin_b, pwout_b,
                                           w1t, w2t, w1sum, mx, sel_idx, sel_w, out);
    } else {
        moe_r3<<<NPAT*LL, 256, 0, stream>>>(x, dw_w, dw_b, ln_g, ln_b,
                                            pwin_b, pwout_b, w1t, w2t,
                                            sel_idx, sel_w, out);
    }
}

// Round 8
// 493.509 us; speedup vs baseline: 1.5077x; 1.5077x over previous
//
#include <hip/hip_runtime.h>

#define NB 2
#define CCH 64
#define LL 8
#define HH 160
#define WW 160
#define PP 8
#define NPH 20
#define NPW 20
#define NPAT 800
#define NE 8
#define HWX 25600
#define CSTRIDE 204800

typedef float f32x4  __attribute__((ext_vector_type(4)));
typedef float f32x16 __attribute__((ext_vector_type(16)));
typedef short bf16x8 __attribute__((ext_vector_type(8)));

__device__ __host__ __forceinline__ unsigned short f2bf(float f) {
    unsigned u = __builtin_bit_cast(unsigned, f);
    u = (u + 0x7FFFu + ((u >> 16) & 1u)) >> 16;
    return (unsigned short)u;
}
__device__ __forceinline__ float dpp_xor1(float v) {  // quad_perm [1,0,3,2]
    int s = __builtin_bit_cast(int, v);
    return __builtin_bit_cast(float, __builtin_amdgcn_update_dpp(s, s, 0xB1, 0xF, 0xF, false));
}
// Y/G LDS swizzle: spreads banks over both i and j of s
__device__ __forceinline__ int xsw(int s) { return ((s & 7) ^ ((s >> 3) & 7)) << 2; }

// ---------------- Prep: w1t (interleaved a/g), w2t, T-decomposition conv table ----------------
// tbl layout: ((e*64+c)*2 + ks)*512 + lane*8 + j   (A-frag order for mfma_16x16x32)
__global__ __launch_bounds__(256)
void prep_kernel(const float* __restrict__ pwin_w, const float* __restrict__ pwout_w,
                 const float* __restrict__ dw_w,
                 unsigned short* __restrict__ w1t, unsigned short* __restrict__ w2t,
                 unsigned short* __restrict__ tbl)
{
    int idx = blockIdx.x * 256 + threadIdx.x;    // grid 2048 -> 524288
    {
        int j = idx & 7, lane = (idx >> 3) & 63, ks = (idx >> 9) & 1;
        int c = (idx >> 10) & 63, e = (idx >> 16) & 7;
        int m = lane & 15;                        // j_out (valid < 8)
        int k = ks*32 + ((lane >> 4) << 3) + j;   // (di, jj)
        int di = k >> 3, jj = k & 7;
        int dj = jj - m + 3;
        float v = 0.f;
        if (m < 8 && di < 7 && dj >= 0 && dj < 7)
            v = dw_w[(e*CCH + c)*49 + di*7 + dj];
        tbl[idx] = f2bf(v);
    }
    if (idx < NE*128*64) {
        int e = idx >> 13, r = (idx >> 6) & 127, c = idx & 63;
        int orig = (r & 1) ? 64 + (r >> 1) : (r >> 1);
        w1t[idx] = f2bf(pwin_w[(e << 13) + orig*64 + c]);
    }
    if (idx < NE*64*64) w2t[idx] = f2bf(pwout_w[idx]);
}

// ---------------- Router ----------------
__global__ __launch_bounds__(256)
void router_kernel(const float* __restrict__ x,
                   const float* __restrict__ rw,
                   const float* __restrict__ rb,
                   int* __restrict__ sel_idx,
                   float* __restrict__ sel_w)
{
    int n = blockIdx.x;
    int b = n / (NPH*NPW);
    int rem = n - b*(NPH*NPW);
    int ph = rem / NPW, pw = rem - ph*NPW;
    int t = threadIdx.x;
    int c = t >> 2, part = t & 3;

    const float* xl0 = x + ((size_t)(b*CCH + c)*LL)*HWX + (size_t)(ph*PP)*WW + pw*PP;
    float s = 0.f;
    for (int l = part*2; l < part*2 + 2; ++l) {
        const float* xl = xl0 + (size_t)l*HWX;
        #pragma unroll
        for (int i = 0; i < 8; ++i) {
            float4 v0 = *(const float4*)(xl + i*WW);
            float4 v1 = *(const float4*)(xl + i*WW + 4);
            s += v0.x+v0.y+v0.z+v0.w + v1.x+v1.y+v1.z+v1.w;
        }
    }
    s += __shfl_xor(s, 1);
    s += __shfl_xor(s, 2);

    __shared__ float meanc[CCH];
    __shared__ float logits[NE];
    if (part == 0) meanc[c] = s * (1.f/512.f);
    __syncthreads();
    if (t < NE) {
        float acc = rb[t];
        for (int cc = 0; cc < CCH; ++cc) acc += meanc[cc] * rw[t*CCH + cc];
        logits[t] = acc;
    }
    __syncthreads();
    if (t == 0) {
        float m0 = -1e30f; int i0 = 0;
        #pragma unroll
        for (int e = 0; e < NE; ++e) { float v = logits[e]; if (v > m0) { m0 = v; i0 = e; } }
        float m1 = -1e30f; int i1 = 0;
        #pragma unroll
        for (int e = 0; e < NE; ++e) { if (e != i0) { float v = logits[e]; if (v > m1) { m1 = v; i1 = e; } } }
        float dd = __expf(m1 - m0);
        float inv = 1.f / (1.f + dd);
        sel_idx[n*2]   = i0;  sel_idx[n*2+1] = i1;
        sel_w[n*2]     = inv; sel_w[n*2+1]   = dd * inv;
    }
}

// ---------------- Main kernel: 1 block/patch, l-halves, solo-wave GEMM ----------------
// LDS 64 KiB: xb bf16 [64c][8r][4lq][8j] (32K) | Yd bf16 [4lq][64s][64c] swz (32K)
__global__ __launch_bounds__(256)
void moe_v7(const float* __restrict__ x,
            const float* __restrict__ ln_g,
            const float* __restrict__ ln_b,
            const float* __restrict__ pwin_b,
            const float* __restrict__ pwout_b,
            const unsigned short* __restrict__ w1t,
            const unsigned short* __restrict__ w2t,
            const unsigned short* __restrict__ tbl,
            const int* __restrict__ sel_idx,
            const float* __restrict__ sel_w,
            float* __restrict__ out)
{
    __shared__ __align__(16) unsigned smem[16384];   // 64 KiB
    unsigned* xb = smem;                             // [0, 8192) dwords
    unsigned* Yd = smem + 8192;                      // [8192, 16384) dwords

    int bid = blockIdx.x;
    int n = (bid & 7)*100 + (bid >> 3);              // XCD-bijective swizzle (800 = 8*100)
    int b = n / 400;
    int rem = n - b*400;
    int ph = rem / 20, pw = rem - (rem/20)*20;

    int t = threadIdx.x;
    int lane = t & 63;
    int wv = __builtin_amdgcn_readfirstlane(t >> 6); // wave id 0..3
    int cbase = wv*16;
    int laneM = lane & 31, hi = lane >> 5;
    int col16 = lane & 15, grp = lane >> 4;
    int iL = col16 >> 2, lq = col16 & 3;             // conv n-decode: i-low, l-quarter
    int i0 = lane >> 3, j0 = lane & 7;
    bool oddl = (lane & 1) != 0;
    int srow_b = (oddl ? 32 : 0) + 4*hi;

    size_t xpb = ((size_t)(b*CCH)*LL)*HWX + (size_t)(ph*PP)*WW + pw*PP;

    int e0 = __builtin_amdgcn_readfirstlane(sel_idx[n*2]);
    int e1 = __builtin_amdgcn_readfirstlane(sel_idx[n*2+1]);
    float wgt0 = sel_w[n*2], wgt1 = sel_w[n*2+1];

    #pragma unroll 1
    for (int lh = 0; lh < 2; ++lh) {
        // ---- stage x half -> xb bf16 [c][r][lq][j] ----
        #pragma unroll
        for (int k2 = 0; k2 < 8; ++k2) {
            int it = t + 256*k2;
            int c = it >> 5, lq2 = (it >> 3) & 3, r = it & 7;
            const float* rp = x + xpb + (size_t)c*CSTRIDE + (size_t)(4*lh + lq2)*HWX + r*WW;
            float4 v0 = *(const float4*)rp;
            float4 v1 = *(const float4*)(rp + 4);
            uint4 bu;
            bu.x = (unsigned)f2bf(v0.x) | ((unsigned)f2bf(v0.y) << 16);
            bu.y = (unsigned)f2bf(v0.z) | ((unsigned)f2bf(v0.w) << 16);
            bu.z = (unsigned)f2bf(v1.x) | ((unsigned)f2bf(v1.y) << 16);
            bu.w = (unsigned)f2bf(v1.z) | ((unsigned)f2bf(v1.w) << 16);
            *(uint4*)&xb[c*128 + r*16 + lq2*4] = bu;
        }
        __syncthreads();   // B1: xb ready; prior half fully retired

        int myl = 4*lh + wv;
        f32x16 oacc[2][2];
        #pragma unroll
        for (int a = 0; a < 2; ++a)
            #pragma unroll
            for (int bb = 0; bb < 2; ++bb)
                #pragma unroll
                for (int i = 0; i < 16; ++i) oacc[a][bb][i] = 0.f;

        #pragma unroll 1
        for (int pass = 0; pass < 2; ++pass) {
            int e     = pass ? e1 : e0;
            float we  = pass ? wgt1 : wgt0;

            // ---- conv: T-form MFMA + LN, 16 channels/wave over all 4 lq ----
            const unsigned short* te = tbl + (((size_t)(e*CCH + cbase)) << 10);
            float gv[8], bv[8];
            #pragma unroll
            for (int nt = 0; nt < 2; ++nt)
                #pragma unroll
                for (int r = 0; r < 4; ++r) {
                    int s = (nt*4 + iL)*8 + grp*4 + r;
                    gv[nt*4+r] = ln_g[e*64 + (s & 63)];
                    bv[nt*4+r] = ln_b[e*64 + (s & 63)];
                }

            #pragma unroll 2
            for (int m = 0; m < 16; ++m) {
                int c = cbase + m;
                uint4 af0 = *(const uint4*)(te + (m*2 + 0)*512 + lane*8);
                uint4 af1 = *(const uint4*)(te + (m*2 + 1)*512 + lane*8);
                f32x4 ac0, ac1;
                ac0[0]=0.f; ac0[1]=0.f; ac0[2]=0.f; ac0[3]=0.f;
                ac1[0]=0.f; ac1[1]=0.f; ac1[2]=0.f; ac1[3]=0.f;
                #pragma unroll
                for (int ks = 0; ks < 2; ++ks) {
                    uint4 af = ks ? af1 : af0;
                    #pragma unroll
                    for (int nt = 0; nt < 2; ++nt) {
                        int row = nt*4 + iL + ks*4 + grp - 3;
                        bool ok = (unsigned)row < 8u;
                        uint4 bu = *(const uint4*)&xb[c*128 + (row & 7)*16 + lq*4];
                        if (!ok) { bu.x = 0u; bu.y = 0u; bu.z = 0u; bu.w = 0u; }
                        if (nt == 0)
                            ac0 = __builtin_amdgcn_mfma_f32_16x16x32_bf16(
                                __builtin_bit_cast(bf16x8, af), __builtin_bit_cast(bf16x8, bu), ac0, 0, 0, 0);
                        else
                            ac1 = __builtin_amdgcn_mfma_f32_16x16x32_bf16(
                                __builtin_bit_cast(bf16x8, af), __builtin_bit_cast(bf16x8, bu), ac1, 0, 0, 0);
                    }
                }
                // LN stats over 64 spatial (rows m>=8 are exact zeros -> harmless)
                float sum = ac0[0]+ac0[1]+ac0[2]+ac0[3]+ac1[0]+ac1[1]+ac1[2]+ac1[3];
                float sq = 0.f;
                #pragma unroll
                for (int r = 0; r < 4; ++r) { sq = fmaf(ac0[r], ac0[r], sq); sq = fmaf(ac1[r], ac1[r], sq); }
                sum += __shfl_xor(sum, 4);  sq += __shfl_xor(sq, 4);
                sum += __shfl_xor(sum, 8);  sq += __shfl_xor(sq, 8);
                sum += __shfl_xor(sum, 16); sq += __shfl_xor(sq, 16);
                sum += __shfl_xor(sum, 32); sq += __shfl_xor(sq, 32);
                float mu  = sum * 0.015625f;
                float var = fmaxf(fmaf(sq, 0.015625f, -mu*mu), 0.f);
                float inv = rsqrtf(var + 1e-5f);
                float nmu = -mu * inv;
                if (grp < 2) {
                    unsigned short* Yh = (unsigned short*)Yd;
                    #pragma unroll
                    for (int nt = 0; nt < 2; ++nt)
                        #pragma unroll
                        for (int r = 0; r < 4; ++r) {
                            float d = nt ? ac1[r] : ac0[r];
                            float y = fmaf(fmaf(d, inv, nmu), gv[nt*4+r], bv[nt*4+r]);
                            int s = (nt*4 + iL)*8 + grp*4 + r;
                            int dw = lq*2048 + s*32 + ((c >> 1) ^ xsw(s));
                            Yh[dw*2 + (c & 1)] = f2bf(y);
                        }
                }
            }
            __syncthreads();   // B2: Y complete for this pass

            // ---- solo-wave GEMMs on l = myl ----
            unsigned* sl = Yd + wv*2048;
            // hoist A-frags (full Y needed before G overwrites the slice)
            uint4 aY0[4], aY1[4];
            #pragma unroll
            for (int ks = 0; ks < 4; ++ks) {
                int kd = 8*ks + 4*hi;
                int sA = laneM, sB = 32 + laneM;
                aY0[ks] = *(const uint4*)&sl[sA*32 + (kd ^ xsw(sA))];
                aY1[ks] = *(const uint4*)&sl[sB*32 + (kd ^ xsw(sB))];
            }
            const unsigned short* w1e = w1t + ((size_t)e << 13);
            const unsigned short* w2e = w2t + ((size_t)e << 12);

            #pragma unroll 1
            for (int dt = 0; dt < 4; ++dt) {
                uint4 b1f[4];
                #pragma unroll
                for (int ks = 0; ks < 4; ++ks)
                    b1f[ks] = *(const uint4*)(w1e + (32*dt + laneM)*64 + 16*ks + 8*hi);
                int dp = 32*dt + laneM;
                int borig = (dp & 1) ? 64 + (dp >> 1) : (dp >> 1);
                float bias1 = pwin_b[e*128 + borig];

                f32x16 acc0, acc1;
                #pragma unroll
                for (int i = 0; i < 16; ++i) { acc0[i]=0.f; acc1[i]=0.f; }
                #pragma unroll
                for (int ks = 0; ks < 4; ++ks) {
                    bf16x8 bvf = __builtin_bit_cast(bf16x8, b1f[ks]);
                    acc0 = __builtin_amdgcn_mfma_f32_32x32x16_bf16(
                        __builtin_bit_cast(bf16x8, aY0[ks]), bvf, acc0, 0, 0, 0);
                    acc1 = __builtin_amdgcn_mfma_f32_32x32x16_bf16(
                        __builtin_bit_cast(bf16x8, aY1[ks]), bvf, acc1, 0, 0, 0);
                }
                // gate -> G into own slice (Y dead: A-frags hoisted)
                int kg  = 16*dt + (laneM >> 1);
                int kdg = kg >> 1, kbit = kg & 1;
                #pragma unroll
                for (int r = 0; r < 16; ++r) {
                    float h0 = acc0[r] + bias1;
                    float h1 = acc1[r] + bias1;
                    float p0 = dpp_xor1(h0);
                    float p1 = dpp_xor1(h1);
                    float A0 = oddl ? p0 : h0, G0 = oddl ? h0 : p0;
                    float A1 = oddl ? p1 : h1, G1 = oddl ? h1 : p1;
                    float ga = __fdividef(A0, 1.f + __expf(-A0)) * G0;
                    float gb = __fdividef(A1, 1.f + __expf(-A1)) * G1;
                    float val = oddl ? gb : ga;
                    int srow = srow_b + (r & 3) + 8*(r >> 2);
                    int dwg = srow*32 + (kdg ^ xsw(srow));
                    ((unsigned short*)sl)[dwg*2 + kbit] = f2bf(val);
                }
            }
            // ---- GEMM2 (reads own G) ----
            #pragma unroll
            for (int ct = 0; ct < 2; ++ct) {
                uint4 b2f[4];
                #pragma unroll
                for (int ks = 0; ks < 4; ++ks)
                    b2f[ks] = *(const uint4*)(w2e + (32*ct + laneM)*64 + 16*ks + 8*hi);
                float bias2 = pwout_b[e*64 + 32*ct + laneM];
                #pragma unroll
                for (int st = 0; st < 2; ++st) {
                    f32x16 g;
                    #pragma unroll
                    for (int i = 0; i < 16; ++i) g[i] = 0.f;
                    #pragma unroll
                    for (int ks = 0; ks < 4; ++ks) {
                        int sG = 32*st + laneM;
                        int kd = 8*ks + 4*hi;
                        uint4 ag = *(const uint4*)&sl[sG*32 + (kd ^ xsw(sG))];
                        g = __builtin_amdgcn_mfma_f32_32x32x16_bf16(
                            __builtin_bit_cast(bf16x8, ag), __builtin_bit_cast(bf16x8, b2f[ks]), g, 0, 0, 0);
                    }
                    #pragma unroll
                    for (int i = 0; i < 16; ++i)
                        oacc[st][ct][i] = fmaf(we, g[i] + bias2, oacc[st][ct][i]);
                }
            }
            if (pass == 0) __syncthreads();   // B3: all waves done before conv pass1 rewrites Y
        }

        // ---- epilogue: fp32 transpose through own slice, residual, store ----
        {
            float* slf = (float*)(Yd + wv*2048);
            size_t obase = xpb + (size_t)myl*HWX;
            #pragma unroll 1
            for (int ct = 0; ct < 2; ++ct) {
                #pragma unroll
                for (int r = 0; r < 16; ++r) {
                    int s0 = 4*hi + (r & 3) + 8*(r >> 2);
                    slf[laneM*64 + (s0 ^ laneM)]        = oacc[0][ct][r];
                    slf[laneM*64 + ((32 + s0) ^ laneM)] = oacc[1][ct][r];
                }
                #pragma unroll 4
                for (int cc = 0; cc < 32; ++cc) {
                    float v = slf[cc*64 + (lane ^ cc)];
                    int c = 32*ct + cc;
                    size_t ga = obase + (size_t)c*CSTRIDE + i0*WW + j0;
                    out[ga] = x[ga] + v;
                }
            }
        }
    }
}

extern "C" void kernel_launch(void* const* d_in, const int* in_sizes, int n_in,
                              void* d_out, int out_size, void* d_ws, size_t ws_size,
                              hipStream_t stream) {
    const float* x        = (const float*)d_in[0];
    const float* router_w = (const float*)d_in[1];
    const float* router_b = (const float*)d_in[2];
    const float* dw_w     = (const float*)d_in[3];
    const float* ln_g     = (const float*)d_in[5];
    const float* ln_b     = (const float*)d_in[6];
    const float* pwin_w   = (const float*)d_in[7];
    const float* pwin_b   = (const float*)d_in[8];
    const float* pwout_w  = (const float*)d_in[9];
    const float* pwout_b  = (const float*)d_in[10];
    float* out = (float*)d_out;

    char* ws = (char*)d_ws;
    int*            sel_idx = (int*)ws;                        // [0, 6400)
    float*          sel_w   = (float*)(ws + 6400);             // [6400, 12800)
    unsigned short* w1t     = (unsigned short*)(ws + 12800);   // 131072 B
    unsigned short* w2t     = (unsigned short*)(ws + 143872);  // 65536 B
    unsigned short* tbl     = (unsigned short*)(ws + 209408);  // 1048576 B -> ends 1257984

    prep_kernel<<<2048, 256, 0, stream>>>(pwin_w, pwout_w, dw_w, w1t, w2t, tbl);
    router_kernel<<<NPAT, 256, 0, stream>>>(x, router_w, router_b, sel_idx, sel_w);
    moe_v7<<<NPAT, 256, 0, stream>>>(x, ln_g, ln_b, pwin_b, pwout_b,
                                     w1t, w2t, tbl, sel_idx, sel_w, out);
}

// Round 9
// 401.669 us; speedup vs baseline: 1.8524x; 1.2286x over previous
//
#include <hip/hip_runtime.h>

#define NB 2
#define CCH 64
#define LL 8
#define HH 160
#define WW 160
#define PP 8
#define NPH 20
#define NPW 20
#define NPAT 800
#define NE 8
#define HWX 25600
#define CSTRIDE 204800

typedef float f32x4  __attribute__((ext_vector_type(4)));
typedef float f32x16 __attribute__((ext_vector_type(16)));
typedef short bf16x8 __attribute__((ext_vector_type(8)));

__device__ __host__ __forceinline__ unsigned short f2bf(float f) {
    unsigned u = __builtin_bit_cast(unsigned, f);
    u = (u + 0x7FFFu + ((u >> 16) & 1u)) >> 16;
    return (unsigned short)u;
}
__device__ __forceinline__ float dpp_xor1(float v) {  // quad_perm [1,0,3,2]
    int s = __builtin_bit_cast(int, v);
    return __builtin_bit_cast(float, __builtin_amdgcn_update_dpp(s, s, 0xB1, 0xF, 0xF, false));
}
__device__ __forceinline__ int xsw(int s) { return ((s & 7) ^ ((s >> 3) & 7)) << 2; }

// ---------------- Prep: w1t (interleaved a/g rows), w2t, T-form conv table ----------------
// tbl: ((e*64+c)*2 + ks)*512 + lane*8 + j  (A-frag for mfma_16x16x32: m=lane&15 (j_out), k=(di,jj))
__global__ __launch_bounds__(256)
void prep_kernel(const float* __restrict__ pwin_w, const float* __restrict__ pwout_w,
                 const float* __restrict__ dw_w,
                 unsigned short* __restrict__ w1t, unsigned short* __restrict__ w2t,
                 unsigned short* __restrict__ tbl)
{
    int idx = blockIdx.x * 256 + threadIdx.x;    // grid 2048 -> 524288
    {
        int j = idx & 7, lane = (idx >> 3) & 63, ks = (idx >> 9) & 1;
        int c = (idx >> 10) & 63, e = (idx >> 16) & 7;
        int m = lane & 15;                        // j_out (valid < 8)
        int k = ks*32 + ((lane >> 4) << 3) + j;   // (di, jj)
        int di = k >> 3, jj = k & 7;
        int dj = jj - m + 3;
        float v = 0.f;
        if (m < 8 && di < 7 && dj >= 0 && dj < 7)
            v = dw_w[(e*CCH + c)*49 + di*7 + dj];
        tbl[idx] = f2bf(v);
    }
    if (idx < NE*128*64) {
        int e = idx >> 13, r = (idx >> 6) & 127, c = idx & 63;
        int orig = (r & 1) ? 64 + (r >> 1) : (r >> 1);
        w1t[idx] = f2bf(pwin_w[(e << 13) + orig*64 + c]);
    }
    if (idx < NE*64*64) w2t[idx] = f2bf(pwout_w[idx]);
}

// ---------------- Router ----------------
__global__ __launch_bounds__(256)
void router_kernel(const float* __restrict__ x,
                   const float* __restrict__ rw,
                   const float* __restrict__ rb,
                   int* __restrict__ sel_idx,
                   float* __restrict__ sel_w)
{
    int n = blockIdx.x;
    int b = n / (NPH*NPW);
    int rem = n - b*(NPH*NPW);
    int ph = rem / NPW, pw = rem - ph*NPW;
    int t = threadIdx.x;
    int c = t >> 2, part = t & 3;

    const float* xl0 = x + ((size_t)(b*CCH + c)*LL)*HWX + (size_t)(ph*PP)*WW + pw*PP;
    float s = 0.f;
    for (int l = part*2; l < part*2 + 2; ++l) {
        const float* xl = xl0 + (size_t)l*HWX;
        #pragma unroll
        for (int i = 0; i < 8; ++i) {
            float4 v0 = *(const float4*)(xl + i*WW);
            float4 v1 = *(const float4*)(xl + i*WW + 4);
            s += v0.x+v0.y+v0.z+v0.w + v1.x+v1.y+v1.z+v1.w;
        }
    }
    s += __shfl_xor(s, 1);
    s += __shfl_xor(s, 2);

    __shared__ float meanc[CCH];
    __shared__ float logits[NE];
    if (part == 0) meanc[c] = s * (1.f/512.f);
    __syncthreads();
    if (t < NE) {
        float acc = rb[t];
        for (int cc = 0; cc < CCH; ++cc) acc += meanc[cc] * rw[t*CCH + cc];
        logits[t] = acc;
    }
    __syncthreads();
    if (t == 0) {
        float m0 = -1e30f; int i0 = 0;
        #pragma unroll
        for (int e = 0; e < NE; ++e) { float v = logits[e]; if (v > m0) { m0 = v; i0 = e; } }
        float m1 = -1e30f; int i1 = 0;
        #pragma unroll
        for (int e = 0; e < NE; ++e) { if (e != i0) { float v = logits[e]; if (v > m1) { m1 = v; i1 = e; } } }
        float dd = __expf(m1 - m0);
        float inv = 1.f / (1.f + dd);
        sel_idx[n*2]   = i0;  sel_idx[n*2+1] = i1;
        sel_w[n*2]     = inv; sel_w[n*2+1]   = dd * inv;
    }
}

// ---------------- Main: block = (b, ph, pw-pair, l); 32 KiB LDS; wave = (patch, role) ----------------
// LDS: xs bf16 [64c][8i][16jq] (16K) | Y/G bf16 2 slices x 8K (16K); epilogue: whole 32K as fp32 obuf
__global__ __launch_bounds__(256, 3)
void moe_v9(const float* __restrict__ x,
            const float* __restrict__ ln_g,
            const float* __restrict__ ln_b,
            const float* __restrict__ pwin_b,
            const float* __restrict__ pwout_b,
            const unsigned short* __restrict__ w1t,
            const unsigned short* __restrict__ w2t,
            const unsigned short* __restrict__ tbl,
            const int* __restrict__ sel_idx,
            const float* __restrict__ sel_w,
            float* __restrict__ out)
{
    __shared__ __align__(16) unsigned smem[8192];    // 32 KiB
    unsigned* xs = smem;                             // [0,4096) dwords
    unsigned* Yr = smem + 4096;                      // [4096,8192): slices p*2048
    float* obuf  = (float*)smem;                     // epilogue reuse (all 8192 dwords)

    int bid = blockIdx.x;
    int nn = (bid & 7)*400 + (bid >> 3);             // XCD-bijective (3200 = 8*400)
    int l  = nn & 7;
    int r2 = nn >> 3;                                // 0..399
    int pwp = r2 % 10;
    int r3  = r2 / 10;
    int ph  = r3 % 20;
    int b   = r3 / 20;

    int t = threadIdx.x;
    int lane = t & 63;
    int wv = __builtin_amdgcn_readfirstlane(t >> 6);
    int p  = wv & 1;                                 // patch within pair
    int h  = wv >> 1;                                // role / c-half / dt-pair / ct
    int col16 = lane & 15, grp = lane >> 4;
    int io = col16 & 7;                              // conv output col (i_o); col16>=8 duplicate
    int laneM = lane & 31, hi = lane >> 5;
    bool oddl = (lane & 1) != 0;
    int srow_b = (oddl ? 32 : 0) + 4*hi;

    int np = b*400 + ph*20 + pwp*2 + p;              // this wave's patch index
    size_t xpb = ((size_t)(b*CCH)*LL + l)*HWX + (size_t)(ph*PP)*WW + pwp*16;

    // ---- stage pair-strip -> xs bf16 [c][i][16jq] ----
    #pragma unroll
    for (int k = 0; k < 16; ++k) {
        int id = t + 256*k;
        int q2 = id & 7, i = (id >> 3) & 7, c = id >> 6;
        float2 v = *(const float2*)(x + xpb + (size_t)c*CSTRIDE + i*WW + q2*2);
        xs[c*64 + i*8 + q2] = (unsigned)f2bf(v.x) | ((unsigned)f2bf(v.y) << 16);
    }
    __syncthreads();                                 // B1

    int e0 = __builtin_amdgcn_readfirstlane(sel_idx[np*2]);
    int e1 = __builtin_amdgcn_readfirstlane(sel_idx[np*2+1]);
    float wA = sel_w[np*2], wB = sel_w[np*2+1];

    f32x16 oacc[2];
    #pragma unroll
    for (int st = 0; st < 2; ++st)
        #pragma unroll
        for (int i = 0; i < 16; ++i) oacc[st][i] = 0.f;

    unsigned* sl = Yr + p*2048;

    #pragma unroll 1
    for (int pass = 0; pass < 2; ++pass) {
        int e    = pass ? e1 : e0;
        float we = pass ? wB : wA;

        // ---- conv (T-form MFMA, N = i_o) + LN -> Y slice p ----
        const unsigned short* te = tbl + (((size_t)(e*CCH + 32*h)) << 10);
        float gv[4], bv[4];
        #pragma unroll
        for (int r = 0; r < 4; ++r) {
            int s = (io*8 + grp*4 + r) & 63;
            gv[r] = ln_g[e*64 + s];
            bv[r] = ln_b[e*64 + s];
        }
        #pragma unroll 2
        for (int m = 0; m < 32; ++m) {
            int c = 32*h + m;
            uint4 af0 = *(const uint4*)(te + (m*2 + 0)*512 + lane*8);
            uint4 af1 = *(const uint4*)(te + (m*2 + 1)*512 + lane*8);
            f32x4 ac; ac[0]=0.f; ac[1]=0.f; ac[2]=0.f; ac[3]=0.f;
            #pragma unroll
            for (int ks = 0; ks < 2; ++ks) {
                int row = io + ks*4 + grp - 3;
                uint4 bu = *(const uint4*)&xs[c*64 + (row & 7)*8 + p*4];
                if (!((unsigned)row < 8u)) { bu.x=0u; bu.y=0u; bu.z=0u; bu.w=0u; }
                uint4 af = ks ? af1 : af0;
                ac = __builtin_amdgcn_mfma_f32_16x16x32_bf16(
                    __builtin_bit_cast(bf16x8, af), __builtin_bit_cast(bf16x8, bu), ac, 0, 0, 0);
            }
            // LN over 64 spatial: in-reg r-sum (rows>=8 are exact zeros) + butterfly over
            // lane bits {0,1,2 (i_o), 4,5 (grp)}; bit 3 (dup-col flag) excluded.
            float sum = ac[0]+ac[1]+ac[2]+ac[3];
            float sq  = 0.f;
            #pragma unroll
            for (int r = 0; r < 4; ++r) sq = fmaf(ac[r], ac[r], sq);
            sum += __shfl_xor(sum, 1);  sq += __shfl_xor(sq, 1);
            sum += __shfl_xor(sum, 2);  sq += __shfl_xor(sq, 2);
            sum += __shfl_xor(sum, 4);  sq += __shfl_xor(sq, 4);
            sum += __shfl_xor(sum, 16); sq += __shfl_xor(sq, 16);
            sum += __shfl_xor(sum, 32); sq += __shfl_xor(sq, 32);
            float mu  = sum * 0.015625f;
            float var = fmaxf(fmaf(sq, 0.015625f, -mu*mu), 0.f);
            float inv = rsqrtf(var + 1e-5f);
            float nmu = -mu * inv;
            if (col16 < 8 && grp < 2) {
                unsigned short* Yh = (unsigned short*)smem;
                #pragma unroll
                for (int r = 0; r < 4; ++r) {
                    float y = fmaf(fmaf(ac[r], inv, nmu), gv[r], bv[r]);
                    int s = io*8 + grp*4 + r;
                    int dw = 4096 + p*2048 + s*32 + ((c >> 1) ^ xsw(s));
                    Yh[dw*2 + (c & 1)] = f2bf(y);
                }
            }
        }
        __syncthreads();                             // B2: Y slices complete

        // ---- hoist A-frags (both roles read full Y slice before G overwrites) ----
        uint4 aY0[4], aY1[4];
        #pragma unroll
        for (int ks = 0; ks < 4; ++ks) {
            int kd = 8*ks + 4*hi;
            aY0[ks] = *(const uint4*)&sl[laneM*32 + (kd ^ xsw(laneM))];
            aY1[ks] = *(const uint4*)&sl[(32 + laneM)*32 + (kd ^ xsw(32 + laneM))];
        }
        __syncthreads();                             // B2b: hoist done

        // ---- GEMM1 (role h: dt = 2h, 2h+1) + gate -> G (disjoint kdg bit4 per role) ----
        const unsigned short* w1e = w1t + ((size_t)e << 13);
        #pragma unroll
        for (int k01 = 0; k01 < 2; ++k01) {
            int dt = 2*h + k01;
            uint4 b1f[4];
            #pragma unroll
            for (int ks = 0; ks < 4; ++ks)
                b1f[ks] = *(const uint4*)(w1e + (32*dt + laneM)*64 + 16*ks + 8*hi);
            int dp = 32*dt + laneM;
            int borig = (dp & 1) ? 64 + (dp >> 1) : (dp >> 1);
            float bias1 = pwin_b[e*128 + borig];

            f32x16 acc0, acc1;
            #pragma unroll
            for (int i = 0; i < 16; ++i) { acc0[i]=0.f; acc1[i]=0.f; }
            #pragma unroll
            for (int ks = 0; ks < 4; ++ks) {
                bf16x8 bvf = __builtin_bit_cast(bf16x8, b1f[ks]);
                acc0 = __builtin_amdgcn_mfma_f32_32x32x16_bf16(
                    __builtin_bit_cast(bf16x8, aY0[ks]), bvf, acc0, 0, 0, 0);
                acc1 = __builtin_amdgcn_mfma_f32_32x32x16_bf16(
                    __builtin_bit_cast(bf16x8, aY1[ks]), bvf, acc1, 0, 0, 0);
            }
            int kg  = 16*dt + (laneM >> 1);
            int kdg = kg >> 1, kbit = kg & 1;
            #pragma unroll
            for (int r = 0; r < 16; ++r) {
                float h0 = acc0[r] + bias1;
                float h1 = acc1[r] + bias1;
                float p0 = dpp_xor1(h0);
                float p1 = dpp_xor1(h1);
                float A0 = oddl ? p0 : h0, G0 = oddl ? h0 : p0;
                float A1 = oddl ? p1 : h1, G1 = oddl ? h1 : p1;
                float ga = __fdividef(A0, 1.f + __expf(-A0)) * G0;
                float gb = __fdividef(A1, 1.f + __expf(-A1)) * G1;
                float val = oddl ? gb : ga;
                int srow = srow_b + (r & 3) + 8*(r >> 2);
                int dwg = srow*32 + (kdg ^ xsw(srow));
                ((unsigned short*)sl)[dwg*2 + kbit] = f2bf(val);
            }
        }
        __syncthreads();                             // B3: G complete

        // ---- GEMM2 (role h: ct = h) ----
        const unsigned short* w2e = w2t + ((size_t)e << 12);
        int cn = 32*h + laneM;
        uint4 b2f[4];
        #pragma unroll
        for (int ks = 0; ks < 4; ++ks)
            b2f[ks] = *(const uint4*)(w2e + cn*64 + 16*ks + 8*hi);
        float bias2 = pwout_b[e*64 + cn];
        #pragma unroll
        for (int st = 0; st < 2; ++st) {
            f32x16 g;
            #pragma unroll
            for (int i = 0; i < 16; ++i) g[i] = 0.f;
            #pragma unroll
            for (int ks = 0; ks < 4; ++ks) {
                int sG = 32*st + laneM;
                int kd = 8*ks + 4*hi;
                uint4 ag = *(const uint4*)&sl[sG*32 + (kd ^ xsw(sG))];
                g = __builtin_amdgcn_mfma_f32_32x32x16_bf16(
                    __builtin_bit_cast(bf16x8, ag), __builtin_bit_cast(bf16x8, b2f[ks]), g, 0, 0, 0);
            }
            #pragma unroll
            for (int i = 0; i < 16; ++i)
                oacc[st][i] = fmaf(we, g[i] + bias2, oacc[st][i]);
        }
        __syncthreads();                             // B4: G reads done (pass1 conv / obuf safe)
    }

    // ---- epilogue: whole-LDS fp32 obuf, XOR-within-row swizzle, 64B-coalesced global I/O ----
    {
        int cn = 32*h + laneM;
        #pragma unroll
        for (int st = 0; st < 2; ++st)
            #pragma unroll
            for (int r = 0; r < 16; ++r) {
                int s = 32*st + 4*hi + (r & 3) + 8*(r >> 2);
                int i = s >> 3, j = s & 7;
                obuf[cn*128 + i*16 + ((p*8 + j) ^ (cn & 15))] = oacc[st][r];
            }
        __syncthreads();                             // B5
        #pragma unroll 4
        for (int rr = 0; rr < 32; ++rr) {
            int row = rr*16 + (t >> 4);              // 0..511 = (c, i)
            int c = row >> 3, i = row & 7;
            int q16 = t & 15;
            float v = obuf[c*128 + i*16 + (q16 ^ (c & 15))];
            size_t ga = xpb + (size_t)c*CSTRIDE + i*WW + q16;
            out[ga] = x[ga] + v;
        }
    }
}

extern "C" void kernel_launch(void* const* d_in, const int* in_sizes, int n_in,
                              void* d_out, int out_size, void* d_ws, size_t ws_size,
                              hipStream_t stream) {
    const float* x        = (const float*)d_in[0];
    const float* router_w = (const float*)d_in[1];
    const float* router_b = (const float*)d_in[2];
    const float* dw_w     = (const float*)d_in[3];
    const float* ln_g     = (const float*)d_in[5];
    const float* ln_b     = (const float*)d_in[6];
    const float* pwin_w   = (const float*)d_in[7];
    const float* pwin_b   = (const float*)d_in[8];
    const float* pwout_w  = (const float*)d_in[9];
    const float* pwout_b  = (const float*)d_in[10];
    float* out = (float*)d_out;

    char* ws = (char*)d_ws;
    int*            sel_idx = (int*)ws;                        // [0, 6400)
    float*          sel_w   = (float*)(ws + 6400);             // [6400, 12800)
    unsigned short* w1t     = (unsigned short*)(ws + 12800);   // 131072 B
    unsigned short* w2t     = (unsigned short*)(ws + 143872);  // 65536 B
    unsigned short* tbl     = (unsigned short*)(ws + 209408);  // 1048576 B -> ends 1257984

    prep_kernel<<<2048, 256, 0, stream>>>(pwin_w, pwout_w, dw_w, w1t, w2t, tbl);
    router_kernel<<<NPAT, 256, 0, stream>>>(x, router_w, router_b, sel_idx, sel_w);
    moe_v9<<<3200, 256, 0, stream>>>(x, ln_g, ln_b, pwin_b, pwout_b,
                                     w1t, w2t, tbl, sel_idx, sel_w, out);
}

// Round 10
// 329.770 us; speedup vs baseline: 2.2563x; 1.2180x over previous
//
#include <hip/hip_runtime.h>

#define NB 2
#define CCH 64
#define LL 8
#define HH 160
#define WW 160
#define PP 8
#define NPH 20
#define NPW 20
#define NPAT 800
#define NE 8
#define HWX 25600
#define CSTRIDE 204800

typedef float f32x4  __attribute__((ext_vector_type(4)));
typedef float f32x16 __attribute__((ext_vector_type(16)));
typedef short bf16x8 __attribute__((ext_vector_type(8)));

__device__ __host__ __forceinline__ unsigned short f2bf(float f) {
    unsigned u = __builtin_bit_cast(unsigned, f);
    u = (u + 0x7FFFu + ((u >> 16) & 1u)) >> 16;
    return (unsigned short)u;
}
__device__ __forceinline__ float dpp_xor1(float v) {  // quad_perm [1,0,3,2]
    int s = __builtin_bit_cast(int, v);
    return __builtin_bit_cast(float, __builtin_amdgcn_update_dpp(s, s, 0xB1, 0xF, 0xF, false));
}
__device__ __forceinline__ int xsw(int s) { return ((s & 7) ^ ((s >> 3) & 7)) << 2; }

// ---------------- Prep: w1t (interleaved a/g rows), w2t, T-form conv table ----------------
// tbl: ((e*64+c)*2 + ks)*512 + lane*8 + j  (A-frag for mfma_16x16x32: m=lane&15 (j_out), k=(di,jj))
__global__ __launch_bounds__(256)
void prep_kernel(const float* __restrict__ pwin_w, const float* __restrict__ pwout_w,
                 const float* __restrict__ dw_w,
                 unsigned short* __restrict__ w1t, unsigned short* __restrict__ w2t,
                 unsigned short* __restrict__ tbl)
{
    int idx = blockIdx.x * 256 + threadIdx.x;    // grid 2048 -> 524288
    {
        int j = idx & 7, lane = (idx >> 3) & 63, ks = (idx >> 9) & 1;
        int c = (idx >> 10) & 63, e = (idx >> 16) & 7;
        int m = lane & 15;                        // j_out (valid < 8)
        int k = ks*32 + ((lane >> 4) << 3) + j;   // (di, jj)
        int di = k >> 3, jj = k & 7;
        int dj = jj - m + 3;
        float v = 0.f;
        if (m < 8 && di < 7 && dj >= 0 && dj < 7)
            v = dw_w[(e*CCH + c)*49 + di*7 + dj];
        tbl[idx] = f2bf(v);
    }
    if (idx < NE*128*64) {
        int e = idx >> 13, r = (idx >> 6) & 127, c = idx & 63;
        int orig = (r & 1) ? 64 + (r >> 1) : (r >> 1);
        w1t[idx] = f2bf(pwin_w[(e << 13) + orig*64 + c]);
    }
    if (idx < NE*64*64) w2t[idx] = f2bf(pwout_w[idx]);
}

// ---------------- Router ----------------
__global__ __launch_bounds__(256)
void router_kernel(const float* __restrict__ x,
                   const float* __restrict__ rw,
                   const float* __restrict__ rb,
                   int* __restrict__ sel_idx,
                   float* __restrict__ sel_w)
{
    int n = blockIdx.x;
    int b = n / (NPH*NPW);
    int rem = n - b*(NPH*NPW);
    int ph = rem / NPW, pw = rem - ph*NPW;
    int t = threadIdx.x;
    int c = t >> 2, part = t & 3;

    const float* xl0 = x + ((size_t)(b*CCH + c)*LL)*HWX + (size_t)(ph*PP)*WW + pw*PP;
    float s = 0.f;
    for (int l = part*2; l < part*2 + 2; ++l) {
        const float* xl = xl0 + (size_t)l*HWX;
        #pragma unroll
        for (int i = 0; i < 8; ++i) {
            float4 v0 = *(const float4*)(xl + i*WW);
            float4 v1 = *(const float4*)(xl + i*WW + 4);
            s += v0.x+v0.y+v0.z+v0.w + v1.x+v1.y+v1.z+v1.w;
        }
    }
    s += __shfl_xor(s, 1);
    s += __shfl_xor(s, 2);

    __shared__ float meanc[CCH];
    __shared__ float logits[NE];
    if (part == 0) meanc[c] = s * (1.f/512.f);
    __syncthreads();
    if (t < NE) {
        float acc = rb[t];
        for (int cc = 0; cc < CCH; ++cc) acc += meanc[cc] * rw[t*CCH + cc];
        logits[t] = acc;
    }
    __syncthreads();
    if (t == 0) {
        float m0 = -1e30f; int i0 = 0;
        #pragma unroll
        for (int e = 0; e < NE; ++e) { float v = logits[e]; if (v > m0) { m0 = v; i0 = e; } }
        float m1 = -1e30f; int i1 = 0;
        #pragma unroll
        for (int e = 0; e < NE; ++e) { if (e != i0) { float v = logits[e]; if (v > m1) { m1 = v; i1 = e; } } }
        float dd = __expf(m1 - m0);
        float inv = 1.f / (1.f + dd);
        sel_idx[n*2]   = i0;  sel_idx[n*2+1] = i1;
        sel_w[n*2]     = inv; sel_w[n*2+1]   = dd * inv;
    }
}

// ---------------- Main v10: block = (b, ph, pw-pair, l-pair); conv N packs (l2, io) ----------------
// LDS 64 KiB: xs bf16 [64c][2l2][8i][8q2] (32K) | Y/G bf16 4 slices x 8K; epilogue: whole as fp32 obuf
__global__ __launch_bounds__(256, 2)
void moe_v10(const float* __restrict__ x,
             const float* __restrict__ ln_g,
             const float* __restrict__ ln_b,
             const float* __restrict__ pwin_b,
             const float* __restrict__ pwout_b,
             const unsigned short* __restrict__ w1t,
             const unsigned short* __restrict__ w2t,
             const unsigned short* __restrict__ tbl,
             const int* __restrict__ sel_idx,
             const float* __restrict__ sel_w,
             float* __restrict__ out)
{
    __shared__ __align__(16) unsigned smem[16384];   // 64 KiB
    unsigned* xs = smem;                             // [0, 8192) dwords
    float* obuf  = (float*)smem;                     // epilogue reuse

    int bid = blockIdx.x;
    int xg = bid & 7, pp = (bid >> 3) & 1, w = bid >> 4;   // w in [0,100)
    int b = xg >> 2, lp = xg & 3;
    int ph = w / 5, pwh = w - ph*5;
    int pwq = pwh*2 + pp;                            // pw-pair index [0,10)

    int t = threadIdx.x;
    int lane = t & 63;
    int wv = __builtin_amdgcn_readfirstlane(t >> 6);
    int p = wv & 1;                                  // patch within pair
    int h = wv >> 1;                                 // conv channel-half AND gemm l2
    int col16 = lane & 15, grp = lane >> 4;
    int io = col16 & 7, l2n = col16 >> 3;            // conv N decode: (l2, i_o)
    int laneM = lane & 31, hi = lane >> 5;
    bool oddl = (lane & 1) != 0;
    int srow_b = (oddl ? 32 : 0) + 4*hi;

    size_t xpb = ((size_t)(b*CCH)*LL + lp*2)*HWX + (size_t)(ph*PP)*WW + pwq*16;
    int np = b*400 + ph*20 + pwq*2 + p;              // this wave's patch

    // ---- stage x (2 patches x 2 l) -> xs bf16 [c][l2][i][q2] ----
    #pragma unroll
    for (int k = 0; k < 16; ++k) {
        int id = t + 256*k;
        int part = id & 3, i = (id >> 2) & 7, l2s = (id >> 5) & 1, c = id >> 6;
        const float* rp = x + xpb + (size_t)c*CSTRIDE + (size_t)l2s*HWX + i*WW + part*4;
        float4 v = *(const float4*)rp;
        uint2 bu;
        bu.x = (unsigned)f2bf(v.x) | ((unsigned)f2bf(v.y) << 16);
        bu.y = (unsigned)f2bf(v.z) | ((unsigned)f2bf(v.w) << 16);
        *(uint2*)&xs[c*128 + l2s*64 + i*8 + part*2] = bu;
    }
    __syncthreads();                                 // B1

    int e0 = __builtin_amdgcn_readfirstlane(sel_idx[np*2]);
    int e1 = __builtin_amdgcn_readfirstlane(sel_idx[np*2+1]);
    float wA = sel_w[np*2], wB = sel_w[np*2+1];

    f32x16 oacc[2][2];
    #pragma unroll
    for (int st = 0; st < 2; ++st)
        #pragma unroll
        for (int ct = 0; ct < 2; ++ct)
            #pragma unroll
            for (int i = 0; i < 16; ++i) oacc[st][ct][i] = 0.f;

    unsigned* sl = smem + 8192 + (p*2 + h)*2048;     // this wave's private slice

    #pragma unroll 1
    for (int pass = 0; pass < 2; ++pass) {
        int e    = pass ? e1 : e0;
        float we = pass ? wB : wA;

        // ---- conv: T-form MFMA, N = (l2, io), both l at once; + LN -> Y slices ----
        const unsigned short* te = tbl + (((size_t)(e*CCH + 32*h)) << 10);
        float gv[4], bv[4];
        #pragma unroll
        for (int r = 0; r < 4; ++r) {
            int s = (io*8 + grp*4 + r) & 63;
            gv[r] = ln_g[e*64 + s];
            bv[r] = ln_b[e*64 + s];
        }
        #pragma unroll 2
        for (int m = 0; m < 32; ++m) {
            int c = 32*h + m;
            uint4 af0 = *(const uint4*)(te + (m*2 + 0)*512 + lane*8);
            uint4 af1 = *(const uint4*)(te + (m*2 + 1)*512 + lane*8);
            f32x4 ac; ac[0]=0.f; ac[1]=0.f; ac[2]=0.f; ac[3]=0.f;
            #pragma unroll
            for (int ks = 0; ks < 2; ++ks) {
                int row = io + ks*4 + grp - 3;
                uint4 bu = *(const uint4*)&xs[c*128 + l2n*64 + (row & 7)*8 + p*4];
                if (!((unsigned)row < 8u)) { bu.x=0u; bu.y=0u; bu.z=0u; bu.w=0u; }
                uint4 af = ks ? af1 : af0;
                ac = __builtin_amdgcn_mfma_f32_16x16x32_bf16(
                    __builtin_bit_cast(bf16x8, af), __builtin_bit_cast(bf16x8, bu), ac, 0, 0, 0);
            }
            // LN stats per (c, l): butterfly bits {0,1,2}(io) + {4,5}(grp); bit 3 (l2) excluded
            float sum = ac[0]+ac[1]+ac[2]+ac[3];
            float sq  = 0.f;
            #pragma unroll
            for (int r = 0; r < 4; ++r) sq = fmaf(ac[r], ac[r], sq);
            sum += __shfl_xor(sum, 1);  sq += __shfl_xor(sq, 1);
            sum += __shfl_xor(sum, 2);  sq += __shfl_xor(sq, 2);
            sum += __shfl_xor(sum, 4);  sq += __shfl_xor(sq, 4);
            sum += __shfl_xor(sum, 16); sq += __shfl_xor(sq, 16);
            sum += __shfl_xor(sum, 32); sq += __shfl_xor(sq, 32);
            float mu  = sum * 0.015625f;
            float var = fmaxf(fmaf(sq, 0.015625f, -mu*mu), 0.f);
            float inv = rsqrtf(var + 1e-5f);
            float nmu = -mu * inv;
            if (grp < 2) {
                unsigned short* Yh = (unsigned short*)smem;
                int sp2 = p*2 + l2n;
                #pragma unroll
                for (int r = 0; r < 4; ++r) {
                    float y = fmaf(fmaf(ac[r], inv, nmu), gv[r], bv[r]);
                    int s = io*8 + grp*4 + r;
                    int dw = 8192 + sp2*2048 + s*32 + ((c >> 1) ^ xsw(s));
                    Yh[dw*2 + (c & 1)] = f2bf(y);
                }
            }
        }
        __syncthreads();                             // B2: all Y slices complete

        // ---- solo GEMMs on private slice (patch p, l = lp*2 + h) ----
        uint4 aY0[4], aY1[4];
        #pragma unroll
        for (int ks = 0; ks < 4; ++ks) {
            int kd = 8*ks + 4*hi;
            aY0[ks] = *(const uint4*)&sl[laneM*32 + (kd ^ xsw(laneM))];
            aY1[ks] = *(const uint4*)&sl[(32 + laneM)*32 + (kd ^ xsw(32 + laneM))];
        }
        const unsigned short* w1e = w1t + ((size_t)e << 13);
        const unsigned short* w2e = w2t + ((size_t)e << 12);

        #pragma unroll 1
        for (int dt = 0; dt < 4; ++dt) {
            uint4 b1f[4];
            #pragma unroll
            for (int ks = 0; ks < 4; ++ks)
                b1f[ks] = *(const uint4*)(w1e + (32*dt + laneM)*64 + 16*ks + 8*hi);
            int dp = 32*dt + laneM;
            int borig = (dp & 1) ? 64 + (dp >> 1) : (dp >> 1);
            float bias1 = pwin_b[e*128 + borig];

            f32x16 acc0, acc1;
            #pragma unroll
            for (int i = 0; i < 16; ++i) { acc0[i]=0.f; acc1[i]=0.f; }
            #pragma unroll
            for (int ks = 0; ks < 4; ++ks) {
                bf16x8 bvf = __builtin_bit_cast(bf16x8, b1f[ks]);
                acc0 = __builtin_amdgcn_mfma_f32_32x32x16_bf16(
                    __builtin_bit_cast(bf16x8, aY0[ks]), bvf, acc0, 0, 0, 0);
                acc1 = __builtin_amdgcn_mfma_f32_32x32x16_bf16(
                    __builtin_bit_cast(bf16x8, aY1[ks]), bvf, acc1, 0, 0, 0);
            }
            int kg  = 16*dt + (laneM >> 1);
            int kdg = kg >> 1, kbit = kg & 1;
            #pragma unroll
            for (int r = 0; r < 16; ++r) {
                float h0 = acc0[r] + bias1;
                float h1 = acc1[r] + bias1;
                float p0 = dpp_xor1(h0);
                float p1 = dpp_xor1(h1);
                float A0 = oddl ? p0 : h0, G0 = oddl ? h0 : p0;
                float A1 = oddl ? p1 : h1, G1 = oddl ? h1 : p1;
                float ga = __fdividef(A0, 1.f + __expf(-A0)) * G0;
                float gb = __fdividef(A1, 1.f + __expf(-A1)) * G1;
                float val = oddl ? gb : ga;
                int srow = srow_b + (r & 3) + 8*(r >> 2);
                int dwg = srow*32 + (kdg ^ xsw(srow));
                ((unsigned short*)sl)[dwg*2 + kbit] = f2bf(val);
            }
        }
        // ---- GEMM2 (reads own G) ----
        #pragma unroll
        for (int ct = 0; ct < 2; ++ct) {
            int cn = 32*ct + laneM;
            uint4 b2f[4];
            #pragma unroll
            for (int ks = 0; ks < 4; ++ks)
                b2f[ks] = *(const uint4*)(w2e + cn*64 + 16*ks + 8*hi);
            float bias2 = pwout_b[e*64 + cn];
            #pragma unroll
            for (int st = 0; st < 2; ++st) {
                f32x16 g;
                #pragma unroll
                for (int i = 0; i < 16; ++i) g[i] = 0.f;
                #pragma unroll
                for (int ks = 0; ks < 4; ++ks) {
                    int sG = 32*st + laneM;
                    int kd = 8*ks + 4*hi;
                    uint4 ag = *(const uint4*)&sl[sG*32 + (kd ^ xsw(sG))];
                    g = __builtin_amdgcn_mfma_f32_32x32x16_bf16(
                        __builtin_bit_cast(bf16x8, ag), __builtin_bit_cast(bf16x8, b2f[ks]), g, 0, 0, 0);
                }
                #pragma unroll
                for (int i = 0; i < 16; ++i)
                    oacc[st][ct][i] = fmaf(we, g[i] + bias2, oacc[st][ct][i]);
            }
        }
        __syncthreads();                             // B3: slice reads done (next conv / epilogue safe)
    }

    // ---- epilogue: per-wave fp32 region [c][s^c], then block-cooperative 64B-coalesced store ----
    {
        float* obr = obuf + (p*2 + h)*4096;
        #pragma unroll
        for (int st = 0; st < 2; ++st)
            #pragma unroll
            for (int ct = 0; ct < 2; ++ct)
                #pragma unroll
                for (int r = 0; r < 16; ++r) {
                    int c = 32*ct + laneM;
                    int s = 32*st + 4*hi + (r & 3) + 8*(r >> 2);
                    obr[c*64 + (s ^ c)] = oacc[st][ct][r];
                }
        __syncthreads();                             // B4
        #pragma unroll 4
        for (int rr = 0; rr < 64; ++rr) {
            int row = rr*16 + (t >> 4);              // 0..1023 = (l2, c, i)
            int l2s = row >> 9;
            int rem = row & 511;
            int c = rem >> 3, i = rem & 7;
            int q16 = t & 15, pq = q16 >> 3, j = q16 & 7;
            float v = obuf[(pq*2 + l2s)*4096 + c*64 + ((i*8 + j) ^ c)];
            size_t ga = xpb + (size_t)c*CSTRIDE + (size_t)l2s*HWX + i*WW + q16;
            out[ga] = x[ga] + v;
        }
    }
}

extern "C" void kernel_launch(void* const* d_in, const int* in_sizes, int n_in,
                              void* d_out, int out_size, void* d_ws, size_t ws_size,
                              hipStream_t stream) {
    const float* x        = (const float*)d_in[0];
    const float* router_w = (const float*)d_in[1];
    const float* router_b = (const float*)d_in[2];
    const float* dw_w     = (const float*)d_in[3];
    const float* ln_g     = (const float*)d_in[5];
    const float* ln_b     = (const float*)d_in[6];
    const float* pwin_w   = (const float*)d_in[7];
    const float* pwin_b   = (const float*)d_in[8];
    const float* pwout_w  = (const float*)d_in[9];
    const float* pwout_b  = (const float*)d_in[10];
    float* out = (float*)d_out;

    char* ws = (char*)d_ws;
    int*            sel_idx = (int*)ws;                        // [0, 6400)
    float*          sel_w   = (float*)(ws + 6400);             // [6400, 12800)
    unsigned short* w1t     = (unsigned short*)(ws + 12800);   // 131072 B
    unsigned short* w2t     = (unsigned short*)(ws + 143872);  // 65536 B
    unsigned short* tbl     = (unsigned short*)(ws + 209408);  // 1048576 B -> ends 1257984

    prep_kernel<<<2048, 256, 0, stream>>>(pwin_w, pwout_w, dw_w, w1t, w2t, tbl);
    router_kernel<<<NPAT, 256, 0, stream>>>(x, router_w, router_b, sel_idx, sel_w);
    moe_v10<<<1600, 256, 0, stream>>>(x, ln_g, ln_b, pwin_b, pwout_b,
                                      w1t, w2t, tbl, sel_idx, sel_w, out);
}

// Round 11
// 210.763 us; speedup vs baseline: 3.5304x; 1.5646x over previous
//
#include <hip/hip_runtime.h>

#define NB 2
#define CCH 64
#define LL 8
#define HH 160
#define WW 160
#define PP 8
#define NPH 20
#define NPW 20
#define NPAT 800
#define NE 8
#define HWX 25600
#define CSTRIDE 204800

typedef float f32x4  __attribute__((ext_vector_type(4)));
typedef float f32x16 __attribute__((ext_vector_type(16)));
typedef short bf16x8 __attribute__((ext_vector_type(8)));

__device__ __host__ __forceinline__ unsigned short f2bf(float f) {
    unsigned u = __builtin_bit_cast(unsigned, f);
    u = (u + 0x7FFFu + ((u >> 16) & 1u)) >> 16;
    return (unsigned short)u;
}
__device__ __forceinline__ unsigned cvtpk(float lo, float hi) {   // r3-proven
    unsigned r;
    asm("v_cvt_pk_bf16_f32 %0, %1, %2" : "=v"(r) : "v"(lo), "v"(hi));
    return r;
}
__device__ __forceinline__ float dpp_xor1(float v) {  // quad_perm [1,0,3,2]
    int s = __builtin_bit_cast(int, v);
    return __builtin_bit_cast(float, __builtin_amdgcn_update_dpp(s, s, 0xB1, 0xF, 0xF, false));
}
__device__ __forceinline__ int xsw(int s) { return ((s & 7) ^ ((s >> 3) & 7)) << 2; }

// ---------------- Prep: w1t (interleaved a/g rows), w2t, paired block-diagonal conv table ----
// tbl: (e*32 + po)*2048 + ks2*512 + lane*8 + j
//   A-frag for mfma_16x16x32, channel pair (cA, cB=cA+16):
//   m16=lane&15: ch=m16>>3, jout=m16&7; k128=ks2*32+(lane>>4)*8+j; kc=k128>>6
//   value = (kc==ch) ? T_{c(ch)}[jout][(di,jj)] : 0
__global__ __launch_bounds__(256)
void prep_kernel(const float* __restrict__ pwin_w, const float* __restrict__ pwout_w,
                 const float* __restrict__ dw_w,
                 unsigned short* __restrict__ w1t, unsigned short* __restrict__ w2t,
                 unsigned short* __restrict__ tbl)
{
    int idx = blockIdx.x * 256 + threadIdx.x;    // grid 2048 -> 524288
    {
        int j = idx & 7, lane = (idx >> 3) & 63, ks2 = (idx >> 9) & 3;
        int po = (idx >> 11) & 31, e = (idx >> 16) & 7;
        int m16 = lane & 15;
        int ch = m16 >> 3, jout = m16 & 7;
        int k128 = ks2*32 + ((lane >> 4) << 3) + j;
        int kc = k128 >> 6, k64 = k128 & 63;
        int di = k64 >> 3, jj = k64 & 7;
        int dj = jj - jout + 3;
        int h = po >> 4, mm = po & 15;
        int c = 32*h + mm + ch*16;
        float v = 0.f;
        if (kc == ch && di < 7 && dj >= 0 && dj < 7)
            v = dw_w[(e*CCH + c)*49 + di*7 + dj];
        tbl[idx] = f2bf(v);
    }
    if (idx < NE*128*64) {
        int e = idx >> 13, r = (idx >> 6) & 127, c = idx & 63;
        int orig = (r & 1) ? 64 + (r >> 1) : (r >> 1);
        w1t[idx] = f2bf(pwin_w[(e << 13) + orig*64 + c]);
    }
    if (idx < NE*64*64) w2t[idx] = f2bf(pwout_w[idx]);
}

// ---------------- Router stage 1: coalesced per-(n,l,c) partial sums (deterministic) --------
__global__ __launch_bounds__(256)
void router_sum(const float* __restrict__ x, float* __restrict__ pmean2)
{
    int bid = blockIdx.x;                        // 320 = b(2) x l(8) x ph(20)
    int ph = bid % 20;
    int r  = bid / 20;
    int l  = r % 8;
    int b  = r / 8;

    __shared__ float acc[1280];                  // [c][pw] = c*20 + pw
    const float* base = x + ((size_t)(b*CCH)*LL + l)*HWX + (size_t)(ph*PP)*WW;
    int t = threadIdx.x;

    #pragma unroll
    for (int k = 0; k < 5; ++k) {
        int s = t + 256*k;                       // < 1280
        int pw = s % 20, c = s / 20;
        const float* rp = base + (size_t)c*CSTRIDE + pw*8;
        float sum = 0.f;
        #pragma unroll
        for (int i = 0; i < 8; ++i) {
            float4 v0 = *(const float4*)(rp + i*WW);
            float4 v1 = *(const float4*)(rp + i*WW + 4);
            sum += v0.x+v0.y+v0.z+v0.w + v1.x+v1.y+v1.z+v1.w;
        }
        acc[c*20 + pw] = sum;
    }
    __syncthreads();
    #pragma unroll
    for (int k = 0; k < 5; ++k) {
        int s = t + 256*k;
        int c = s & 63, pwi = s >> 6;            // c fastest -> coalesced store
        int n = b*400 + ph*20 + pwi;
        pmean2[(size_t)n*512 + l*64 + c] = acc[c*20 + pwi];
    }
}

// ---------------- Router stage 2: logits + top-2 softmax ----------------
__global__ __launch_bounds__(64)
void router_top(const float* __restrict__ pmean2,
                const float* __restrict__ rw, const float* __restrict__ rb,
                int* __restrict__ sel_idx, float* __restrict__ sel_w)
{
    int n = blockIdx.x;
    int t = threadIdx.x;                         // 64
    __shared__ float mc[64];
    __shared__ float lg[8];
    const float* pb = pmean2 + (size_t)n*512;
    float s = 0.f;
    #pragma unroll
    for (int l = 0; l < 8; ++l) s += pb[l*64 + t];
    mc[t] = s * (1.f/512.f);
    __syncthreads();
    if (t < 8) {
        float a = rb[t];
        for (int c = 0; c < 64; ++c) a += mc[c] * rw[t*64 + c];
        lg[t] = a;
    }
    __syncthreads();
    if (t == 0) {
        float m0 = -1e30f; int i0 = 0;
        #pragma unroll
        for (int e = 0; e < NE; ++e) { float v = lg[e]; if (v > m0) { m0 = v; i0 = e; } }
        float m1 = -1e30f; int i1 = 0;
        #pragma unroll
        for (int e = 0; e < NE; ++e) { if (e != i0) { float v = lg[e]; if (v > m1) { m1 = v; i1 = e; } } }
        float dd = __expf(m1 - m0);
        float inv = 1.f / (1.f + dd);
        sel_idx[n*2]   = i0;  sel_idx[n*2+1] = i1;
        sel_w[n*2]     = inv; sel_w[n*2+1]   = dd * inv;
    }
}

// ---------------- Main v11: v10 structure + paired conv + conflict swizzles ----------------
// LDS 64KB+64B: xs bf16 [64c][2l2][8i][8q2] swz (32K) | 4 Y/G slices x 8K | zero pad 64B
__global__ __launch_bounds__(256, 2)
void moe_v11(const float* __restrict__ x,
             const float* __restrict__ ln_g,
             const float* __restrict__ ln_b,
             const float* __restrict__ pwin_b,
             const float* __restrict__ pwout_b,
             const unsigned short* __restrict__ w1t,
             const unsigned short* __restrict__ w2t,
             const unsigned short* __restrict__ tbl,
             const int* __restrict__ sel_idx,
             const float* __restrict__ sel_w,
             float* __restrict__ out)
{
    __shared__ __align__(16) unsigned smem[16400];   // 64 KiB + 64 B zero pad
    unsigned* xs = smem;                             // [0, 8192) dwords
    float* obuf  = (float*)smem;                     // epilogue reuse [0,16384)

    int bid = blockIdx.x;
    int xg = bid & 7, pp = (bid >> 3) & 1, w = bid >> 4;   // w in [0,100)
    int b = xg >> 2, lp = xg & 3;
    int ph = w / 5, pwh = w - ph*5;
    int pwq = pwh*2 + pp;

    int t = threadIdx.x;
    int lane = t & 63;
    int wv = __builtin_amdgcn_readfirstlane(t >> 6);
    int p = wv & 1;                                  // patch within pair
    int h = wv >> 1;                                 // conv channel-half AND gemm l2
    int col16 = lane & 15, grp = lane >> 4;
    int io = col16 & 7, l2n = col16 >> 3;            // conv N decode: (l2, i_o)
    int laneM = lane & 31, hi = lane >> 5;
    bool oddl = (lane & 1) != 0;
    int srow_b = (oddl ? 32 : 0) + 4*hi;
    int sx = (h & 1) << 2;                           // wave slice-parity xor (slice p*2+h)

    size_t xpb = ((size_t)(b*CCH)*LL + lp*2)*HWX + (size_t)(ph*PP)*WW + pwq*16;
    int np = b*400 + ph*20 + pwq*2 + p;

    // zero pad region for OOB conv rows
    if (t < 16) smem[16384 + t] = 0u;

    // ---- stage x (2 patches x 2 l) -> xs bf16 [c][l2][i][q2] with bank swizzle ----
    #pragma unroll
    for (int k = 0; k < 16; ++k) {
        int id = t + 256*k;
        int part = id & 3, i = (id >> 2) & 7, l2s = (id >> 5) & 1, c = id >> 6;
        const float* rp = x + xpb + (size_t)c*CSTRIDE + (size_t)l2s*HWX + i*WW + part*4;
        float4 v = *(const float4*)rp;
        uint2 bu;
        bu.x = cvtpk(v.x, v.y);
        bu.y = cvtpk(v.z, v.w);
        int off = (part*2) ^ (((l2s ^ (i >> 2)) & 1) << 2);
        *(uint2*)&xs[c*128 + l2s*64 + i*8 + off] = bu;
    }
    __syncthreads();                                 // B1

    int e0 = __builtin_amdgcn_readfirstlane(sel_idx[np*2]);
    int e1 = __builtin_amdgcn_readfirstlane(sel_idx[np*2+1]);
    float wA = sel_w[np*2], wB = sel_w[np*2+1];

    f32x16 oacc[2][2];
    #pragma unroll
    for (int st = 0; st < 2; ++st)
        #pragma unroll
        for (int ct = 0; ct < 2; ++ct)
            #pragma unroll
            for (int i = 0; i < 16; ++i) oacc[st][ct][i] = 0.f;

    unsigned* sl = smem + 8192 + (p*2 + h)*2048;     // wave's private slice

    // conv loop-invariant row offsets (swizzled) + OOB flags
    int rowoff[2]; bool okr[2];
    #pragma unroll
    for (int ks = 0; ks < 2; ++ks) {
        int row = io + ks*4 + grp - 3;
        int rw = row & 7;
        rowoff[ks] = l2n*64 + rw*8 + (((p ^ l2n ^ (rw >> 2)) & 1) << 2);
        okr[ks] = (unsigned)row < 8u;
    }
    int sb = io*8 + (grp & 1)*4;                     // write s-base (+r)
    int chs = grp >> 1;                              // this lane's channel select (0:cA 1:cB)
    int sp2 = p*2 + l2n;                             // conv write slice
    int csx = l2n << 2;                              // conv write slice-parity xor

    #pragma unroll 1
    for (int pass = 0; pass < 2; ++pass) {
        int e    = pass ? e1 : e0;
        float we = pass ? wB : wA;

        // ---- conv: paired block-diagonal MFMA (M=16: two channels) + per-channel LN ----
        const unsigned short* te = tbl + (((size_t)(e*32 + h*16)) << 11);
        float gv[4], bv[4];
        #pragma unroll
        for (int r = 0; r < 4; ++r) {
            gv[r] = ln_g[e*64 + sb + r];
            bv[r] = ln_b[e*64 + sb + r];
        }

        #pragma unroll 2
        for (int m = 0; m < 16; ++m) {
            int cA = 32*h + m;
            const unsigned short* tm = te + ((size_t)m << 11);
            f32x4 ac; ac[0]=0.f; ac[1]=0.f; ac[2]=0.f; ac[3]=0.f;
            #pragma unroll
            for (int ks2 = 0; ks2 < 4; ++ks2) {
                int c = cA + ((ks2 & 2) ? 16 : 0);
                int ks = ks2 & 1;
                int aB = okr[ks] ? (c*128 + rowoff[ks]) : 16384;
                uint4 bu = *(const uint4*)&xs[aB];
                uint4 af = *(const uint4*)(tm + ks2*512 + lane*8);
                ac = __builtin_amdgcn_mfma_f32_16x16x32_bf16(
                    __builtin_bit_cast(bf16x8, af), __builtin_bit_cast(bf16x8, bu), ac, 0, 0, 0);
            }
            // LN stats per (channel, l): butterfly bits {0,1,2}=io, {4}=grp&1;
            // bit3 (l2) and bit5 (channel) excluded.
            float sum = ac[0]+ac[1]+ac[2]+ac[3];
            float sq  = 0.f;
            #pragma unroll
            for (int r = 0; r < 4; ++r) sq = fmaf(ac[r], ac[r], sq);
            sum += __shfl_xor(sum, 1);  sq += __shfl_xor(sq, 1);
            sum += __shfl_xor(sum, 2);  sq += __shfl_xor(sq, 2);
            sum += __shfl_xor(sum, 4);  sq += __shfl_xor(sq, 4);
            sum += __shfl_xor(sum, 16); sq += __shfl_xor(sq, 16);
            float mu  = sum * 0.015625f;
            float var = fmaxf(fmaf(sq, 0.015625f, -mu*mu), 0.f);
            float inv = rsqrtf(var + 1e-5f);
            float nmu = -mu * inv;
            int myc = cA + (chs ? 16 : 0);
            unsigned short* Yh = (unsigned short*)smem;
            int cd = (myc >> 1), cb = myc & 1;
            #pragma unroll
            for (int r = 0; r < 4; ++r) {
                float y = fmaf(fmaf(ac[r], inv, nmu), gv[r], bv[r]);
                int s = sb + r;
                int dw = 8192 + sp2*2048 + s*32 + ((cd ^ xsw(s)) ^ csx);
                Yh[dw*2 + cb] = (unsigned short)cvtpk(y, y);
            }
        }
        __syncthreads();                             // B2: all Y slices complete

        // ---- solo GEMMs on private slice (patch p, l = lp*2 + h) ----
        uint4 aY0[4], aY1[4];
        #pragma unroll
        for (int ks = 0; ks < 4; ++ks) {
            int kd = 8*ks + 4*hi;
            aY0[ks] = *(const uint4*)&sl[laneM*32 + ((kd ^ xsw(laneM)) ^ sx)];
            aY1[ks] = *(const uint4*)&sl[(32 + laneM)*32 + ((kd ^ xsw(32 + laneM)) ^ sx)];
        }
        const unsigned short* w1e = w1t + ((size_t)e << 13);
        const unsigned short* w2e = w2t + ((size_t)e << 12);

        #pragma unroll 1
        for (int dt = 0; dt < 4; ++dt) {
            uint4 b1f[4];
            #pragma unroll
            for (int ks = 0; ks < 4; ++ks)
                b1f[ks] = *(const uint4*)(w1e + (32*dt + laneM)*64 + 16*ks + 8*hi);
            int dp = 32*dt + laneM;
            int borig = (dp & 1) ? 64 + (dp >> 1) : (dp >> 1);
            float bias1 = pwin_b[e*128 + borig];

            f32x16 acc0, acc1;
            #pragma unroll
            for (int i = 0; i < 16; ++i) { acc0[i]=0.f; acc1[i]=0.f; }
            #pragma unroll
            for (int ks = 0; ks < 4; ++ks) {
                bf16x8 bvf = __builtin_bit_cast(bf16x8, b1f[ks]);
                acc0 = __builtin_amdgcn_mfma_f32_32x32x16_bf16(
                    __builtin_bit_cast(bf16x8, aY0[ks]), bvf, acc0, 0, 0, 0);
                acc1 = __builtin_amdgcn_mfma_f32_32x32x16_bf16(
                    __builtin_bit_cast(bf16x8, aY1[ks]), bvf, acc1, 0, 0, 0);
            }
            int kg  = 16*dt + (laneM >> 1);
            int kdg = kg >> 1, kbit = kg & 1;
            #pragma unroll
            for (int r = 0; r < 16; ++r) {
                float h0 = acc0[r] + bias1;
                float h1 = acc1[r] + bias1;
                float p0 = dpp_xor1(h0);
                float p1 = dpp_xor1(h1);
                float A0 = oddl ? p0 : h0, G0 = oddl ? h0 : p0;
                float A1 = oddl ? p1 : h1, G1 = oddl ? h1 : p1;
                float ga = __fdividef(A0, 1.f + __expf(-A0)) * G0;
                float gb = __fdividef(A1, 1.f + __expf(-A1)) * G1;
                float val = oddl ? gb : ga;
                int srow = srow_b + (r & 3) + 8*(r >> 2);
                int dwg = srow*32 + ((kdg ^ xsw(srow)) ^ sx);
                ((unsigned short*)sl)[dwg*2 + kbit] = (unsigned short)cvtpk(val, val);
            }
        }
        // ---- GEMM2 (reads own G) ----
        #pragma unroll
        for (int ct = 0; ct < 2; ++ct) {
            int cn = 32*ct + laneM;
            uint4 b2f[4];
            #pragma unroll
            for (int ks = 0; ks < 4; ++ks)
                b2f[ks] = *(const uint4*)(w2e + cn*64 + 16*ks + 8*hi);
            float bias2 = pwout_b[e*64 + cn];
            #pragma unroll
            for (int st = 0; st < 2; ++st) {
                f32x16 g;
                #pragma unroll
                for (int i = 0; i < 16; ++i) g[i] = 0.f;
                #pragma unroll
                for (int ks = 0; ks < 4; ++ks) {
                    int sG = 32*st + laneM;
                    int kd = 8*ks + 4*hi;
                    uint4 ag = *(const uint4*)&sl[sG*32 + ((kd ^ xsw(sG)) ^ sx)];
                    g = __builtin_amdgcn_mfma_f32_32x32x16_bf16(
                        __builtin_bit_cast(bf16x8, ag), __builtin_bit_cast(bf16x8, b2f[ks]), g, 0, 0, 0);
                }
                #pragma unroll
                for (int i = 0; i < 16; ++i)
                    oacc[st][ct][i] = fmaf(we, g[i] + bias2, oacc[st][ct][i]);
            }
        }
        __syncthreads();                             // B3: slice reads done
    }

    // ---- epilogue: per-wave fp32 region [c][s^c], block-cooperative 64B-coalesced store ----
    {
        float* obr = obuf + (p*2 + h)*4096;
        #pragma unroll
        for (int st = 0; st < 2; ++st)
            #pragma unroll
            for (int ct = 0; ct < 2; ++ct)
                #pragma unroll
                for (int r = 0; r < 16; ++r) {
                    int c = 32*ct + laneM;
                    int s = 32*st + 4*hi + (r & 3) + 8*(r >> 2);
                    obr[c*64 + (s ^ c)] = oacc[st][ct][r];
                }
        __syncthreads();                             // B4
        #pragma unroll 4
        for (int rr = 0; rr < 64; ++rr) {
            int row = rr*16 + (t >> 4);              // (l2, c, i)
            int l2s = row >> 9;
            int rem = row & 511;
            int c = rem >> 3, i = rem & 7;
            int q16 = t & 15, pq = q16 >> 3, j = q16 & 7;
            float v = obuf[(pq*2 + l2s)*4096 + c*64 + ((i*8 + j) ^ c)];
            size_t ga = xpb + (size_t)c*CSTRIDE + (size_t)l2s*HWX + i*WW + q16;
            out[ga] = x[ga] + v;
        }
    }
}

extern "C" void kernel_launch(void* const* d_in, const int* in_sizes, int n_in,
                              void* d_out, int out_size, void* d_ws, size_t ws_size,
                              hipStream_t stream) {
    const float* x        = (const float*)d_in[0];
    const float* router_w = (const float*)d_in[1];
    const float* router_b = (const float*)d_in[2];
    const float* dw_w     = (const float*)d_in[3];
    const float* ln_g     = (const float*)d_in[5];
    const float* ln_b     = (const float*)d_in[6];
    const float* pwin_w   = (const float*)d_in[7];
    const float* pwin_b   = (const float*)d_in[8];
    const float* pwout_w  = (const float*)d_in[9];
    const float* pwout_b  = (const float*)d_in[10];
    float* out = (float*)d_out;

    char* ws = (char*)d_ws;
    int*            sel_idx = (int*)ws;                        // [0, 6400)
    float*          sel_w   = (float*)(ws + 6400);             // [6400, 12800)
    unsigned short* w1t     = (unsigned short*)(ws + 12800);   // 131072 B
    unsigned short* w2t     = (unsigned short*)(ws + 143872);  // 65536 B
    unsigned short* tbl     = (unsigned short*)(ws + 209408);  // 1048576 B -> 1257984
    float*          pmean2  = (float*)(ws + 1257984);          // 1638400 B -> 2896384

    prep_kernel<<<2048, 256, 0, stream>>>(pwin_w, pwout_w, dw_w, w1t, w2t, tbl);
    router_sum<<<320, 256, 0, stream>>>(x, pmean2);
    router_top<<<NPAT, 64, 0, stream>>>(pmean2, router_w, router_b, sel_idx, sel_w);
    moe_v11<<<1600, 256, 0, stream>>>(x, ln_g, ln_b, pwin_b, pwout_b,
                                      w1t, w2t, tbl, sel_idx, sel_w, out);
}

// Round 12
// 176.286 us; speedup vs baseline: 4.2208x; 1.1956x over previous
//
#include <hip/hip_runtime.h>

#define NB 2
#define CCH 64
#define LL 8
#define HH 160
#define WW 160
#define PP 8
#define NPH 20
#define NPW 20
#define NPAT 800
#define NE 8
#define HWX 25600
#define CSTRIDE 204800

typedef float f32x4  __attribute__((ext_vector_type(4)));
typedef float f32x16 __attribute__((ext_vector_type(16)));
typedef short bf16x8 __attribute__((ext_vector_type(8)));

__device__ __host__ __forceinline__ unsigned short f2bf(float f) {
    unsigned u = __builtin_bit_cast(unsigned, f);
    u = (u + 0x7FFFu + ((u >> 16) & 1u)) >> 16;
    return (unsigned short)u;
}
__device__ __forceinline__ unsigned cvtpk(float lo, float hi) {
    unsigned r;
    asm("v_cvt_pk_bf16_f32 %0, %1, %2" : "=v"(r) : "v"(lo), "v"(hi));
    return r;
}
__device__ __forceinline__ float dpp_xor1(float v) {  // quad_perm [1,0,3,2]
    int s = __builtin_bit_cast(int, v);
    return __builtin_bit_cast(float, __builtin_amdgcn_update_dpp(s, s, 0xB1, 0xF, 0xF, false));
}
__device__ __forceinline__ int xsw(int s) { return ((s & 7) ^ ((s >> 3) & 7)) << 2; }

// ---------------- Prep: w1t (interleaved a/g rows), w2t, paired block-diagonal conv table ----
__global__ __launch_bounds__(256)
void prep_kernel(const float* __restrict__ pwin_w, const float* __restrict__ pwout_w,
                 const float* __restrict__ dw_w,
                 unsigned short* __restrict__ w1t, unsigned short* __restrict__ w2t,
                 unsigned short* __restrict__ tbl)
{
    int idx = blockIdx.x * 256 + threadIdx.x;    // grid 2048 -> 524288
    {
        int j = idx & 7, lane = (idx >> 3) & 63, ks2 = (idx >> 9) & 3;
        int po = (idx >> 11) & 31, e = (idx >> 16) & 7;
        int m16 = lane & 15;
        int ch = m16 >> 3, jout = m16 & 7;
        int k128 = ks2*32 + ((lane >> 4) << 3) + j;
        int kc = k128 >> 6, k64 = k128 & 63;
        int di = k64 >> 3, jj = k64 & 7;
        int dj = jj - jout + 3;
        int h = po >> 4, mm = po & 15;
        int c = 32*h + mm + ch*16;
        float v = 0.f;
        if (kc == ch && di < 7 && dj >= 0 && dj < 7)
            v = dw_w[(e*CCH + c)*49 + di*7 + dj];
        tbl[idx] = f2bf(v);
    }
    if (idx < NE*128*64) {
        int e = idx >> 13, r = (idx >> 6) & 127, c = idx & 63;
        int orig = (r & 1) ? 64 + (r >> 1) : (r >> 1);
        w1t[idx] = f2bf(pwin_w[(e << 13) + orig*64 + c]);
    }
    if (idx < NE*64*64) w2t[idx] = f2bf(pwout_w[idx]);
}

// ---------------- Router stage 1: coalesced per-(n,l,c) partial sums ----------------
__global__ __launch_bounds__(256)
void router_sum(const float* __restrict__ x, float* __restrict__ pmean2)
{
    int bid = blockIdx.x;                        // 320 = b(2) x l(8) x ph(20)
    int ph = bid % 20;
    int r  = bid / 20;
    int l  = r % 8;
    int b  = r / 8;

    __shared__ float acc[1280];
    const float* base = x + ((size_t)(b*CCH)*LL + l)*HWX + (size_t)(ph*PP)*WW;
    int t = threadIdx.x;

    #pragma unroll
    for (int k = 0; k < 5; ++k) {
        int s = t + 256*k;
        int pw = s % 20, c = s / 20;
        const float* rp = base + (size_t)c*CSTRIDE + pw*8;
        float sum = 0.f;
        #pragma unroll
        for (int i = 0; i < 8; ++i) {
            float4 v0 = *(const float4*)(rp + i*WW);
            float4 v1 = *(const float4*)(rp + i*WW + 4);
            sum += v0.x+v0.y+v0.z+v0.w + v1.x+v1.y+v1.z+v1.w;
        }
        acc[c*20 + pw] = sum;
    }
    __syncthreads();
    #pragma unroll
    for (int k = 0; k < 5; ++k) {
        int s = t + 256*k;
        int c = s & 63, pwi = s >> 6;
        int n = b*400 + ph*20 + pwi;
        pmean2[(size_t)n*512 + l*64 + c] = acc[c*20 + pwi];
    }
}

// ---------------- Router stage 2: logits + top-2 softmax ----------------
__global__ __launch_bounds__(64)
void router_top(const float* __restrict__ pmean2,
                const float* __restrict__ rw, const float* __restrict__ rb,
                int* __restrict__ sel_idx, float* __restrict__ sel_w)
{
    int n = blockIdx.x;
    int t = threadIdx.x;
    __shared__ float mc[64];
    __shared__ float lg[8];
    const float* pb = pmean2 + (size_t)n*512;
    float s = 0.f;
    #pragma unroll
    for (int l = 0; l < 8; ++l) s += pb[l*64 + t];
    mc[t] = s * (1.f/512.f);
    __syncthreads();
    if (t < 8) {
        float a = rb[t];
        for (int c = 0; c < 64; ++c) a += mc[c] * rw[t*64 + c];
        lg[t] = a;
    }
    __syncthreads();
    if (t == 0) {
        float m0 = -1e30f; int i0 = 0;
        #pragma unroll
        for (int e = 0; e < NE; ++e) { float v = lg[e]; if (v > m0) { m0 = v; i0 = e; } }
        float m1 = -1e30f; int i1 = 0;
        #pragma unroll
        for (int e = 0; e < NE; ++e) { if (e != i0) { float v = lg[e]; if (v > m1) { m1 = v; i1 = e; } } }
        float dd = __expf(m1 - m0);
        float inv = 1.f / (1.f + dd);
        sel_idx[n*2]   = i0;  sel_idx[n*2+1] = i1;
        sel_w[n*2]     = inv; sel_w[n*2+1]   = dd * inv;
    }
}

// ---------------- Main v12: v11 + single-silu gate + float4 epilogue ----------------
__global__ __launch_bounds__(256, 2)
void moe_v12(const float* __restrict__ x,
             const float* __restrict__ ln_g,
             const float* __restrict__ ln_b,
             const float* __restrict__ pwin_b,
             const float* __restrict__ pwout_b,
             const unsigned short* __restrict__ w1t,
             const unsigned short* __restrict__ w2t,
             const unsigned short* __restrict__ tbl,
             const int* __restrict__ sel_idx,
             const float* __restrict__ sel_w,
             float* __restrict__ out)
{
    __shared__ __align__(16) unsigned smem[16400];   // 64 KiB + 64 B zero pad
    unsigned* xs = smem;                             // [0, 8192) dwords
    float* obuf  = (float*)smem;                     // epilogue reuse [0,16384)

    int bid = blockIdx.x;
    int xg = bid & 7, pp = (bid >> 3) & 1, w = bid >> 4;
    int b = xg >> 2, lp = xg & 3;
    int ph = w / 5, pwh = w - ph*5;
    int pwq = pwh*2 + pp;

    int t = threadIdx.x;
    int lane = t & 63;
    int wv = __builtin_amdgcn_readfirstlane(t >> 6);
    int p = wv & 1;
    int h = wv >> 1;
    int col16 = lane & 15, grp = lane >> 4;
    int io = col16 & 7, l2n = col16 >> 3;
    int laneM = lane & 31, hi = lane >> 5;
    bool oddl = (lane & 1) != 0;
    int srow_b = (oddl ? 32 : 0) + 4*hi;
    int sx = (h & 1) << 2;

    size_t xpb = ((size_t)(b*CCH)*LL + lp*2)*HWX + (size_t)(ph*PP)*WW + pwq*16;
    int np = b*400 + ph*20 + pwq*2 + p;

    if (t < 16) smem[16384 + t] = 0u;

    // ---- stage x -> xs bf16 [c][l2][i][q2] with bank swizzle ----
    #pragma unroll
    for (int k = 0; k < 16; ++k) {
        int id = t + 256*k;
        int part = id & 3, i = (id >> 2) & 7, l2s = (id >> 5) & 1, c = id >> 6;
        const float* rp = x + xpb + (size_t)c*CSTRIDE + (size_t)l2s*HWX + i*WW + part*4;
        float4 v = *(const float4*)rp;
        uint2 bu;
        bu.x = cvtpk(v.x, v.y);
        bu.y = cvtpk(v.z, v.w);
        int off = (part*2) ^ (((l2s ^ (i >> 2)) & 1) << 2);
        *(uint2*)&xs[c*128 + l2s*64 + i*8 + off] = bu;
    }
    __syncthreads();                                 // B1

    int e0 = __builtin_amdgcn_readfirstlane(sel_idx[np*2]);
    int e1 = __builtin_amdgcn_readfirstlane(sel_idx[np*2+1]);
    float wA = sel_w[np*2], wB = sel_w[np*2+1];

    f32x16 oacc[2][2];
    #pragma unroll
    for (int st = 0; st < 2; ++st)
        #pragma unroll
        for (int ct = 0; ct < 2; ++ct)
            #pragma unroll
            for (int i = 0; i < 16; ++i) oacc[st][ct][i] = 0.f;

    unsigned* sl = smem + 8192 + (p*2 + h)*2048;

    int rowoff[2]; bool okr[2];
    #pragma unroll
    for (int ks = 0; ks < 2; ++ks) {
        int row = io + ks*4 + grp - 3;
        int rw = row & 7;
        rowoff[ks] = l2n*64 + rw*8 + (((p ^ l2n ^ (rw >> 2)) & 1) << 2);
        okr[ks] = (unsigned)row < 8u;
    }
    int sb = io*8 + (grp & 1)*4;
    int chs = grp >> 1;
    int sp2 = p*2 + l2n;
    int csx = l2n << 2;

    #pragma unroll 1
    for (int pass = 0; pass < 2; ++pass) {
        int e    = pass ? e1 : e0;
        float we = pass ? wB : wA;

        // ---- conv: paired block-diagonal MFMA + per-channel LN ----
        const unsigned short* te = tbl + (((size_t)(e*32 + h*16)) << 11);
        float gv[4], bv[4];
        #pragma unroll
        for (int r = 0; r < 4; ++r) {
            gv[r] = ln_g[e*64 + sb + r];
            bv[r] = ln_b[e*64 + sb + r];
        }

        #pragma unroll 2
        for (int m = 0; m < 16; ++m) {
            int cA = 32*h + m;
            const unsigned short* tm = te + ((size_t)m << 11);
            f32x4 ac; ac[0]=0.f; ac[1]=0.f; ac[2]=0.f; ac[3]=0.f;
            #pragma unroll
            for (int ks2 = 0; ks2 < 4; ++ks2) {
                int c = cA + ((ks2 & 2) ? 16 : 0);
                int ks = ks2 & 1;
                int aB = okr[ks] ? (c*128 + rowoff[ks]) : 16384;
                uint4 bu = *(const uint4*)&xs[aB];
                uint4 af = *(const uint4*)(tm + ks2*512 + lane*8);
                ac = __builtin_amdgcn_mfma_f32_16x16x32_bf16(
                    __builtin_bit_cast(bf16x8, af), __builtin_bit_cast(bf16x8, bu), ac, 0, 0, 0);
            }
            float sum = ac[0]+ac[1]+ac[2]+ac[3];
            float sq  = 0.f;
            #pragma unroll
            for (int r = 0; r < 4; ++r) sq = fmaf(ac[r], ac[r], sq);
            sum += __shfl_xor(sum, 1);  sq += __shfl_xor(sq, 1);
            sum += __shfl_xor(sum, 2);  sq += __shfl_xor(sq, 2);
            sum += __shfl_xor(sum, 4);  sq += __shfl_xor(sq, 4);
            sum += __shfl_xor(sum, 16); sq += __shfl_xor(sq, 16);
            float mu  = sum * 0.015625f;
            float var = fmaxf(fmaf(sq, 0.015625f, -mu*mu), 0.f);
            float inv = rsqrtf(var + 1e-5f);
            float nmu = -mu * inv;
            int myc = cA + (chs ? 16 : 0);
            unsigned short* Yh = (unsigned short*)smem;
            int cd = (myc >> 1), cb = myc & 1;
            #pragma unroll
            for (int r = 0; r < 4; ++r) {
                float y = fmaf(fmaf(ac[r], inv, nmu), gv[r], bv[r]);
                int s = sb + r;
                int dw = 8192 + sp2*2048 + s*32 + ((cd ^ xsw(s)) ^ csx);
                Yh[dw*2 + cb] = (unsigned short)cvtpk(y, y);
            }
        }
        __syncthreads();                             // B2

        // ---- solo GEMMs on private slice ----
        uint4 aY0[4], aY1[4];
        #pragma unroll
        for (int ks = 0; ks < 4; ++ks) {
            int kd = 8*ks + 4*hi;
            aY0[ks] = *(const uint4*)&sl[laneM*32 + ((kd ^ xsw(laneM)) ^ sx)];
            aY1[ks] = *(const uint4*)&sl[(32 + laneM)*32 + ((kd ^ xsw(32 + laneM)) ^ sx)];
        }
        const unsigned short* w1e = w1t + ((size_t)e << 13);
        const unsigned short* w2e = w2t + ((size_t)e << 12);

        #pragma unroll 1
        for (int dt = 0; dt < 4; ++dt) {
            uint4 b1f[4];
            #pragma unroll
            for (int ks = 0; ks < 4; ++ks)
                b1f[ks] = *(const uint4*)(w1e + (32*dt + laneM)*64 + 16*ks + 8*hi);
            int dp = 32*dt + laneM;
            int borig = (dp & 1) ? 64 + (dp >> 1) : (dp >> 1);
            float bias1 = pwin_b[e*128 + borig];

            f32x16 acc0, acc1;
            #pragma unroll
            for (int i = 0; i < 16; ++i) { acc0[i]=0.f; acc1[i]=0.f; }
            #pragma unroll
            for (int ks = 0; ks < 4; ++ks) {
                bf16x8 bvf = __builtin_bit_cast(bf16x8, b1f[ks]);
                acc0 = __builtin_amdgcn_mfma_f32_32x32x16_bf16(
                    __builtin_bit_cast(bf16x8, aY0[ks]), bvf, acc0, 0, 0, 0);
                acc1 = __builtin_amdgcn_mfma_f32_32x32x16_bf16(
                    __builtin_bit_cast(bf16x8, aY1[ks]), bvf, acc1, 0, 0, 0);
            }
            int kg  = 16*dt + (laneM >> 1);
            int kdg = kg >> 1, kbit = kg & 1;
            #pragma unroll
            for (int r = 0; r < 16; ++r) {
                // single-silu gate: select operands first (identical math to v11)
                float h0 = acc0[r] + bias1;
                float h1 = acc1[r] + bias1;
                float p0 = dpp_xor1(h0);
                float p1 = dpp_xor1(h1);
                float A = oddl ? p1 : h0;
                float G = oddl ? h1 : p0;
                float sg = __builtin_amdgcn_rcpf(1.f + __expf(-A));
                float val = A * sg * G;
                int srow = srow_b + (r & 3) + 8*(r >> 2);
                int dwg = srow*32 + ((kdg ^ xsw(srow)) ^ sx);
                ((unsigned short*)sl)[dwg*2 + kbit] = (unsigned short)cvtpk(val, val);
            }
        }
        // ---- GEMM2 ----
        #pragma unroll
        for (int ct = 0; ct < 2; ++ct) {
            int cn = 32*ct + laneM;
            uint4 b2f[4];
            #pragma unroll
            for (int ks = 0; ks < 4; ++ks)
                b2f[ks] = *(const uint4*)(w2e + cn*64 + 16*ks + 8*hi);
            float bias2 = pwout_b[e*64 + cn];
            #pragma unroll
            for (int st = 0; st < 2; ++st) {
                f32x16 g;
                #pragma unroll
                for (int i = 0; i < 16; ++i) g[i] = 0.f;
                #pragma unroll
                for (int ks = 0; ks < 4; ++ks) {
                    int sG = 32*st + laneM;
                    int kd = 8*ks + 4*hi;
                    uint4 ag = *(const uint4*)&sl[sG*32 + ((kd ^ xsw(sG)) ^ sx)];
                    g = __builtin_amdgcn_mfma_f32_32x32x16_bf16(
                        __builtin_bit_cast(bf16x8, ag), __builtin_bit_cast(bf16x8, b2f[ks]), g, 0, 0, 0);
                }
                #pragma unroll
                for (int i = 0; i < 16; ++i)
                    oacc[st][ct][i] = fmaf(we, g[i] + bias2, oacc[st][ct][i]);
            }
        }
        __syncthreads();                             // B3
    }

    // ---- epilogue: per-wave fp32 region [c][s^c], float4-coalesced global I/O ----
    {
        float* obr = obuf + (p*2 + h)*4096;
        #pragma unroll
        for (int st = 0; st < 2; ++st)
            #pragma unroll
            for (int ct = 0; ct < 2; ++ct)
                #pragma unroll
                for (int r = 0; r < 16; ++r) {
                    int c = 32*ct + laneM;
                    int s = 32*st + 4*hi + (r & 3) + 8*(r >> 2);
                    obr[c*64 + (s ^ c)] = oacc[st][ct][r];
                }
        __syncthreads();                             // B4
        #pragma unroll
        for (int rr = 0; rr < 16; ++rr) {
            int row = rr*64 + (t >> 2);              // 0..1023 = (l2, c, i)
            int l2s = row >> 9;
            int rem = row & 511;
            int c = rem >> 3, i = rem & 7;
            int q4 = (t & 3) * 4;                    // 0,4,8,12
            int pq = q4 >> 3;
            int jb = q4 & 7;
            int ob = (pq*2 + l2s)*4096 + c*64;
            float4 v;
            v.x = obuf[ob + ((i*8 + jb + 0) ^ c)];
            v.y = obuf[ob + ((i*8 + jb + 1) ^ c)];
            v.z = obuf[ob + ((i*8 + jb + 2) ^ c)];
            v.w = obuf[ob + ((i*8 + jb + 3) ^ c)];
            size_t ga = xpb + (size_t)c*CSTRIDE + (size_t)l2s*HWX + i*WW + q4;
            float4 xr = *(const float4*)(x + ga);
            v.x += xr.x; v.y += xr.y; v.z += xr.z; v.w += xr.w;
            *(float4*)(out + ga) = v;
        }
    }
}

extern "C" void kernel_launch(void* const* d_in, const int* in_sizes, int n_in,
                              void* d_out, int out_size, void* d_ws, size_t ws_size,
                              hipStream_t stream) {
    const float* x        = (const float*)d_in[0];
    const float* router_w = (const float*)d_in[1];
    const float* router_b = (const float*)d_in[2];
    const float* dw_w     = (const float*)d_in[3];
    const float* ln_g     = (const float*)d_in[5];
    const float* ln_b     = (const float*)d_in[6];
    const float* pwin_w   = (const float*)d_in[7];
    const float* pwin_b   = (const float*)d_in[8];
    const float* pwout_w  = (const float*)d_in[9];
    const float* pwout_b  = (const float*)d_in[10];
    float* out = (float*)d_out;

    char* ws = (char*)d_ws;
    int*            sel_idx = (int*)ws;                        // [0, 6400)
    float*          sel_w   = (float*)(ws + 6400);             // [6400, 12800)
    unsigned short* w1t     = (unsigned short*)(ws + 12800);   // 131072 B
    unsigned short* w2t     = (unsigned short*)(ws + 143872);  // 65536 B
    unsigned short* tbl     = (unsigned short*)(ws + 209408);  // 1048576 B -> 1257984
    float*          pmean2  = (float*)(ws + 1257984);          // 1638400 B -> 2896384

    prep_kernel<<<2048, 256, 0, stream>>>(pwin_w, pwout_w, dw_w, w1t, w2t, tbl);
    router_sum<<<320, 256, 0, stream>>>(x, pmean2);
    router_top<<<NPAT, 64, 0, stream>>>(pmean2, router_w, router_b, sel_idx, sel_w);
    moe_v12<<<1600, 256, 0, stream>>>(x, ln_g, ln_b, pwin_b, pwout_b,
                                      w1t, w2t, tbl, sel_idx, sel_w, out);
}